// Round 2
// baseline (1351.817 us; speedup 1.0000x reference)
//
#include <hip/hip_runtime.h>
#include <hip/hip_bf16.h>

// ---- problem constants ----
#define BQ 16      // batch
#define CN 96      // channels
#define HQ 48      // quadrant H = W
#define LL 2304    // HQ*HQ
#define NK 4       // scan directions
#define RR 6       // dt rank
#define NNS 8      // state size
#define DPJ 22     // R + 2N
#define CRr 12     // attention rank

using bf16 = __hip_bfloat16;

__device__ __forceinline__ float b2f(bf16 v) { return __bfloat162float(v); }
__device__ __forceinline__ bf16  f2b(float v){ return __float2bfloat16(v); }
__device__ __forceinline__ float bflo(unsigned u){ return __uint_as_float(u << 16); }
__device__ __forceinline__ float bfhi(unsigned u){ return __uint_as_float(u & 0xffff0000u); }
__device__ __forceinline__ float sigf(float x){ return 1.f / (1.f + __expf(-x)); }
__device__ __forceinline__ float siluf(float x){ return x / (1.f + __expf(-x)); }

// ============================================================================
// K1: channel LN + conv1x1 (a-branch with silu, z-branch raw)
// grid (24, 16, 4) = (hh-pair, b, q), block 192
// inputs fp32; stages bf16 into LDS for vectorized matvec
// ============================================================================
__global__ __launch_bounds__(192) void k_lnconv(
    const float* __restrict__ x, const float* __restrict__ ln_g, const float* __restrict__ ln_b,
    const float* __restrict__ p1w, const float* __restrict__ p1b,
    const float* __restrict__ p2w, const float* __restrict__ p2b,
    bf16* __restrict__ a_out, float* __restrict__ z0_out)
{
    const int hh2 = blockIdx.x;           // 0..23 (covers 2 rows each)
    const int b = blockIdx.y, q = blockIdx.z;
    const int h0 = (q >> 1) * HQ, w0 = (q & 1) * HQ;
    const int tid = threadIdx.x;
    const int qb = q * BQ + b;

    __shared__ alignas(16) bf16 hn[CN * 96];    // [c][p], p = local pos 0..95 (2 rows x 48)
    __shared__ alignas(16) bf16 wl[CN * 200];   // [c][row 0..191, pad to 200]
    __shared__ float mu[96], rs[96];

    // stage weights transposed: wl[c][d] = p1, wl[c][96+d] = p2in
    for (int t = tid; t < CN * CN; t += 192) {
        int d = t / CN, c = t % CN;
        wl[c * 200 + d]      = f2b(p1w[(q * CN + d) * CN + c]);
        wl[c * 200 + 96 + d] = f2b(p2w[(q * CN + d) * CN + c]);
    }
    // stage x tile (fp32 -> fp32 stats later need full precision? keep bf16, fine)
    for (int t = tid; t < CN * 96; t += 192) {
        int c = t / 96, p = t % 96;
        hn[t] = f2b(x[((b * CN + c) * 96 + h0 + 2 * hh2 + p / 48) * 96 + w0 + (p % 48)]);
    }
    __syncthreads();
    // LN stats per position
    if (tid < 96) {
        float s = 0.f, s2 = 0.f;
        for (int c = 0; c < CN; ++c) { float v = b2f(hn[c * 96 + tid]); s += v; s2 += v * v; }
        float m = s * (1.f / 96.f);
        float var = s2 * (1.f / 96.f) - m * m;
        mu[tid] = m; rs[tid] = rsqrtf(var + 1e-6f);
    }
    __syncthreads();
    // normalize in place
    for (int t = tid; t < CN * 96; t += 192) {
        int c = t / 96, p = t % 96;
        float g = ln_g[q * CN + c], bb = ln_b[q * CN + c];
        hn[t] = f2b((b2f(hn[t]) - mu[p]) * rs[p] * g + bb);
    }
    __syncthreads();
    // matvec: thread -> 8 output rows x 12 positions
    const int rg = tid >> 3, pg = tid & 7;
    const int row0 = rg * 8, pp0 = pg * 12;
    float acc[8][12];
    #pragma unroll
    for (int i = 0; i < 8; ++i)
        #pragma unroll
        for (int j = 0; j < 12; ++j) acc[i][j] = 0.f;

    for (int c = 0; c < CN; ++c) {
        uint4 wv = *reinterpret_cast<const uint4*>(&wl[c * 200 + row0]);
        float w[8];
        w[0] = bflo(wv.x); w[1] = bfhi(wv.x);
        w[2] = bflo(wv.y); w[3] = bfhi(wv.y);
        w[4] = bflo(wv.z); w[5] = bfhi(wv.z);
        w[6] = bflo(wv.w); w[7] = bfhi(wv.w);
        uint2 ha = *reinterpret_cast<const uint2*>(&hn[c * 96 + pp0]);
        uint2 hb = *reinterpret_cast<const uint2*>(&hn[c * 96 + pp0 + 4]);
        uint2 hc = *reinterpret_cast<const uint2*>(&hn[c * 96 + pp0 + 8]);
        float hv[12];
        hv[0] = bflo(ha.x); hv[1] = bfhi(ha.x); hv[2]  = bflo(ha.y); hv[3]  = bfhi(ha.y);
        hv[4] = bflo(hb.x); hv[5] = bfhi(hb.x); hv[6]  = bflo(hb.y); hv[7]  = bfhi(hb.y);
        hv[8] = bflo(hc.x); hv[9] = bfhi(hc.x); hv[10] = bflo(hc.y); hv[11] = bfhi(hc.y);
        #pragma unroll
        for (int i = 0; i < 8; ++i)
            #pragma unroll
            for (int j = 0; j < 12; ++j)
                acc[i][j] = fmaf(w[i], hv[j], acc[i][j]);
    }
    // epilogue
    #pragma unroll
    for (int i = 0; i < 8; ++i) {
        int row = row0 + i;
        bool isA = row < 96;
        int d = isA ? row : row - 96;
        float bias = isA ? p1b[q * CN + d] : p2b[q * CN + d];
        #pragma unroll
        for (int j = 0; j < 12; ++j) {
            int p = pp0 + j;
            int l = (2 * hh2 + p / 48) * 48 + (p % 48);
            float v = acc[i][j] + bias;
            int oidx = (qb * CN + d) * LL + l;
            if (isA) a_out[oidx] = f2b(siluf(v));
            else     z0_out[oidx] = v;
        }
    }
}

// ============================================================================
// K2: depthwise 3x3 SAME (per quadrant) + bias + silu + block_idx transform
// writes zt (transformed space) and ztT (its 48x48 transpose)
// grid (96, 16, 4) = (c, b, q), block 256
// ============================================================================
__global__ __launch_bounds__(256) void k_dwconv(
    const float* __restrict__ z0, const float* __restrict__ dww, const float* __restrict__ dwb,
    const int* __restrict__ bidx, bf16* __restrict__ zt, bf16* __restrict__ ztT)
{
    const int c = blockIdx.x, b = blockIdx.y, q = blockIdx.z;
    const int tid = threadIdx.x;
    const int base = ((q * BQ + b) * CN + c) * LL;
    __shared__ float zin[LL];
    __shared__ float zo[LL];
    for (int t = tid; t < LL; t += 256) zin[t] = z0[base + t];
    float wk[9];
    #pragma unroll
    for (int i = 0; i < 9; ++i) wk[i] = dww[(q * CN + c) * 9 + i];
    const float bias = dwb[q * CN + c];
    __syncthreads();
    for (int t = tid; t < LL; t += 256) {
        int hh = t / 48, ww = t % 48;
        float s = bias;
        #pragma unroll
        for (int dy = -1; dy <= 1; ++dy)
            #pragma unroll
            for (int dx = -1; dx <= 1; ++dx) {
                int yy = hh + dy, xx = ww + dx;
                if (yy >= 0 && yy < 48 && xx >= 0 && xx < 48)
                    s = fmaf(wk[(dy + 1) * 3 + (dx + 1)], zin[yy * 48 + xx], s);
            }
        zo[t] = siluf(s);
    }
    __syncthreads();
    const bool even = ((bidx[0] & 1) == 0);
    for (int t = tid; t < LL; t += 256) {
        int i = t / 48, j = t % 48;
        float vz, vzT;
        if (even) { vz = zo[j * 48 + i];               vzT = zo[i * 48 + j]; }
        else      { vz = zo[(47 - i) * 48 + (47 - j)]; vzT = zo[(47 - j) * 48 + (47 - i)]; }
        zt[base + t]  = f2b(vz);
        ztT[base + t] = f2b(vzT);
    }
}

// ============================================================================
// K3: x_dbl = xproj_w @ u_k  (direction mapping + reversal folded in)
// grid (12, 4, 64) = (l-tile, k, q*16+b), block 256
// ============================================================================
__global__ __launch_bounds__(256) void k_xdbl(
    const bf16* __restrict__ zt, const bf16* __restrict__ ztT,
    const float* __restrict__ xprojw, bf16* __restrict__ xdbl)
{
    const int lt = blockIdx.x, k = blockIdx.y, qb = blockIdx.z;
    const int tid = threadIdx.x;
    const int l0 = lt * 192;
    const int q = qb >> 4;
    __shared__ alignas(16) bf16 ul[CN * 200];
    __shared__ alignas(16) bf16 wl[DPJ * CN];
    const bf16* src = (k & 1) ? ztT : zt;
    const bool rev = (k >= 2);
    for (int t = tid; t < CN * 192; t += 256) {
        int c = t / 192, l = t % 192;
        int lsrc = rev ? (LL - 1 - (l0 + l)) : (l0 + l);
        ul[c * 200 + l] = src[(qb * CN + c) * LL + lsrc];
    }
    for (int t = tid; t < DPJ * CN; t += 256)
        wl[t] = f2b(xprojw[(q * NK + k) * DPJ * CN + t]);
    __syncthreads();
    // tiles: 2 d-rows x 8 l : 11 * 24 = 264 tiles
    for (int t = tid; t < 264; t += 256) {
        int dp = t / 24, lg = t % 24;
        int d0 = dp * 2, llp = lg * 8;
        float acc0[8], acc1[8];
        #pragma unroll
        for (int j = 0; j < 8; ++j) { acc0[j] = 0.f; acc1[j] = 0.f; }
        for (int c = 0; c < CN; ++c) {
            float w0 = b2f(wl[d0 * CN + c]);
            float w1 = b2f(wl[(d0 + 1) * CN + c]);
            uint4 uv = *reinterpret_cast<const uint4*>(&ul[c * 200 + llp]);
            float uf[8];
            uf[0] = bflo(uv.x); uf[1] = bfhi(uv.x);
            uf[2] = bflo(uv.y); uf[3] = bfhi(uv.y);
            uf[4] = bflo(uv.z); uf[5] = bfhi(uv.z);
            uf[6] = bflo(uv.w); uf[7] = bfhi(uv.w);
            #pragma unroll
            for (int j = 0; j < 8; ++j) {
                acc0[j] = fmaf(w0, uf[j], acc0[j]);
                acc1[j] = fmaf(w1, uf[j], acc1[j]);
            }
        }
        int ob = (qb * NK + k) * DPJ * LL + l0 + llp;
        #pragma unroll
        for (int j = 0; j < 8; ++j) {
            xdbl[ob + d0 * LL + j]       = f2b(acc0[j]);
            xdbl[ob + (d0 + 1) * LL + j] = f2b(acc1[j]);
        }
    }
}

// ============================================================================
// K4: fused delta(softplus) + selective scan + Ds*u term
// grid (256) = (qb,k), block 384 = 96 c x 4 lanes (2 states each)
// ============================================================================
__global__ __launch_bounds__(384) void k_scan(
    const bf16* __restrict__ zt, const bf16* __restrict__ ztT,
    const bf16* __restrict__ xdbl,
    const float* __restrict__ dtw_g, const float* __restrict__ dtb_g,
    const float* __restrict__ Alog_g, const float* __restrict__ Ds_g,
    bf16* __restrict__ ys)
{
    const int bid = blockIdx.x;
    const int k = bid & 3, qb = bid >> 2;
    const int q = qb >> 4;
    const int tid = threadIdx.x;
    const int c = tid >> 2, p = tid & 3;
    const int qk = q * NK + k;

    __shared__ alignas(16) float2 ud[CN * 49];   // [c][j pad49] x=u, y=delta
    __shared__ alignas(16) float bc[48 * 18];    // [j][v pad18] v<8: B, v>=8: C
    __shared__ float dts[RR * 48];
    __shared__ float wdt[CN * RR];
    __shared__ float dtb[CN];
    __shared__ float yt[CN * 49];

    for (int t = tid; t < CN * RR; t += 384) wdt[t] = dtw_g[qk * CN * RR + t];
    if (tid < CN) dtb[tid] = dtb_g[qk * CN + tid];

    const int n0 = 2 * p;
    const float A0 = -__expf(Alog_g[(qk * CN + c) * NNS + n0]);
    const float A1 = -__expf(Alog_g[(qk * CN + c) * NNS + n0 + 1]);
    const float Dc = Ds_g[qk * CN + c];
    float h0 = 0.f, h1 = 0.f;

    const bf16* src = (k & 1) ? ztT : zt;
    const bool rev = (k >= 2);
    const int ubase = qb * CN * LL;
    const int xbase = (qb * NK + k) * DPJ * LL;
    const int ybase = (qb * NK + k) * CN * LL;

    for (int ch = 0; ch < 48; ++ch) {
        const int l0 = ch * 48;
        // stage u
        for (int t = tid; t < CN * 48; t += 384) {
            int cc = t / 48, j = t % 48;
            int lsrc = rev ? (LL - 1 - (l0 + j)) : (l0 + j);
            ud[cc * 49 + j].x = b2f(src[ubase + cc * LL + lsrc]);
        }
        // stage dts
        if (tid < RR * 48) {
            int r = tid / 48, j = tid % 48;
            dts[tid] = b2f(xdbl[xbase + r * LL + l0 + j]);
        }
        // stage B/C
        for (int t = tid; t < 16 * 48; t += 384) {
            int v = t / 48, j = t % 48;
            bc[j * 18 + v] = b2f(xdbl[xbase + (RR + v) * LL + l0 + j]);
        }
        __syncthreads();
        // delta = softplus(dtw . dts + dtb)
        for (int t = tid; t < CN * 48; t += 384) {
            int cc = t / 48, j = t % 48;
            float accd = dtb[cc];
            #pragma unroll
            for (int r = 0; r < RR; ++r) accd = fmaf(wdt[cc * RR + r], dts[r * 48 + j], accd);
            ud[cc * 49 + j].y = accd > 15.f ? accd : __logf(1.f + __expf(accd));
        }
        __syncthreads();
        // scan
        #pragma unroll 4
        for (int j = 0; j < 48; ++j) {
            float2 f = ud[c * 49 + j];
            float d = f.y, u = f.x;
            float du = d * u;
            float2 B2 = *reinterpret_cast<const float2*>(&bc[j * 18 + n0]);
            float2 C2 = *reinterpret_cast<const float2*>(&bc[j * 18 + 8 + n0]);
            float dA0 = __expf(d * A0), dA1 = __expf(d * A1);
            h0 = fmaf(dA0, h0, du * B2.x);
            h1 = fmaf(dA1, h1, du * B2.y);
            float y = h0 * C2.x + h1 * C2.y;
            y += __shfl_xor(y, 1, 64);
            y += __shfl_xor(y, 2, 64);
            if (p == 0) yt[c * 49 + j] = y + Dc * u;
        }
        __syncthreads();
        // store ys
        for (int t = tid; t < CN * 48; t += 384) {
            int cc = t / 48, j = t % 48;
            ys[ybase + cc * LL + l0 + j] = f2b(yt[cc * 49 + j]);
        }
        __syncthreads();
    }
}

// ============================================================================
// K5: combine 4 directions + LN(ssln) + inverse transform + LN(p2n) + y=a*z
//     + partial spatial sums for attention
// grid (48, 16, 4) = (ww', b, q), block 256
// ============================================================================
__global__ __launch_bounds__(256) void k_combine(
    const bf16* __restrict__ ys, const bf16* __restrict__ a_in,
    const float* __restrict__ ssg, const float* __restrict__ ssb,
    const float* __restrict__ png, const float* __restrict__ pnb,
    const int* __restrict__ bidx,
    bf16* __restrict__ y_out, float* __restrict__ s_buf)
{
    const int ww = blockIdx.x, b = blockIdx.y, q = blockIdx.z;
    const int qb = q * BQ + b;
    const int tid = threadIdx.x;
    __shared__ float o[CN * 48];
    __shared__ float mu[48], rs[48];
    const int ysb = qb * NK * CN * LL;
    for (int t = tid; t < CN * 48; t += 256) {
        int c = t / 48, hh = t % 48;
        float v0 = b2f(ys[ysb + (0 * CN + c) * LL + hh * 48 + ww]);
        float v1 = b2f(ys[ysb + (1 * CN + c) * LL + ww * 48 + hh]);
        float v2 = b2f(ys[ysb + (2 * CN + c) * LL + (LL - 1) - hh * 48 - ww]);
        float v3 = b2f(ys[ysb + (3 * CN + c) * LL + (LL - 1) - ww * 48 - hh]);
        o[t] = v0 + v1 + v2 + v3;
    }
    __syncthreads();
    if (tid < 48) {
        float s = 0.f, s2 = 0.f;
        for (int cc = 0; cc < CN; ++cc) { float v = o[cc * 48 + tid]; s += v; s2 += v * v; }
        float m = s * (1.f / 96.f), var = s2 * (1.f / 96.f) - m * m;
        mu[tid] = m; rs[tid] = rsqrtf(var + 1e-6f);
    }
    __syncthreads();
    for (int t = tid; t < CN * 48; t += 256) {
        int cc = t / 48, hh = t % 48;
        o[t] = (o[t] - mu[hh]) * rs[hh] * ssg[q * CN + cc] + ssb[q * CN + cc];
    }
    __syncthreads();
    if (tid < 48) {
        float s = 0.f, s2 = 0.f;
        for (int cc = 0; cc < CN; ++cc) { float v = o[cc * 48 + tid]; s += v; s2 += v * v; }
        float m = s * (1.f / 96.f), var = s2 * (1.f / 96.f) - m * m;
        mu[tid] = m; rs[tid] = rsqrtf(var + 1e-6f);
    }
    __syncthreads();
    const bool even = ((bidx[0] & 1) == 0);
    for (int t = tid; t < CN * 48; t += 256) {
        int cc = t / 48, hh = t % 48;
        float z2 = (o[t] - mu[hh]) * rs[hh] * png[q * CN + cc] + pnb[q * CN + cc];
        int oidx;
        if (even) oidx = (qb * CN + cc) * LL + ww * 48 + hh;
        else      oidx = (qb * CN + cc) * LL + (47 - hh) * 48 + (47 - ww);
        float yv = b2f(a_in[oidx]) * z2;
        y_out[oidx] = f2b(yv);
        o[t] = yv;
    }
    __syncthreads();
    if (tid < CN) {
        float s = 0.f;
        for (int j = 0; j < 48; ++j) s += o[tid * 48 + j];
        atomicAdd(&s_buf[qb * CN + tid], s);
    }
}

// ============================================================================
// K6: channel attention:  att = sigmoid(w2 @ silu(w1 @ mean(y) + b1) + b2)
// grid (16, 4), block 128
// ============================================================================
__global__ __launch_bounds__(128) void k_attn(
    const float* __restrict__ s_buf,
    const float* __restrict__ w1, const float* __restrict__ b1,
    const float* __restrict__ w2, const float* __restrict__ b2,
    float* __restrict__ att)
{
    const int b = blockIdx.x, q = blockIdx.y;
    const int qb = q * BQ + b;
    const int tid = threadIdx.x;
    __shared__ float sm[CN], tl[CRr];
    if (tid < CN) sm[tid] = s_buf[qb * CN + tid] * (1.f / (float)LL);
    __syncthreads();
    if (tid < CRr) {
        float acc = b1[q * CRr + tid];
        for (int cc = 0; cc < CN; ++cc)
            acc = fmaf(w1[(q * CRr + tid) * CN + cc], sm[cc], acc);
        tl[tid] = siluf(acc);
    }
    __syncthreads();
    if (tid < CN) {
        float acc = b2[q * CN + tid];
        #pragma unroll
        for (int r = 0; r < CRr; ++r)
            acc = fmaf(w2[(q * CN + tid) * CRr + r], tl[r], acc);
        att[qb * CN + tid] = sigf(acc);
    }
}

// ============================================================================
// K7: out = x + y * att
// grid (96, 16, 4) = (c, b, q), block 256
// ============================================================================
__global__ __launch_bounds__(256) void k_final(
    const float* __restrict__ x, const bf16* __restrict__ y_in,
    const float* __restrict__ att, float* __restrict__ out)
{
    const int c = blockIdx.x, b = blockIdx.y, q = blockIdx.z;
    const int h0 = (q >> 1) * HQ, w0 = (q & 1) * HQ;
    const int qb = q * BQ + b;
    const float av = att[qb * CN + c];
    const int ybase = (qb * CN + c) * LL;
    const int xb = (b * CN + c) * 9216 + h0 * 96 + w0;
    for (int t = threadIdx.x; t < LL; t += 256) {
        int hh = t / 48, wwp = t % 48;
        int gi = xb + hh * 96 + wwp;
        out[gi] = x[gi] + b2f(y_in[ybase + t]) * av;
    }
}

// ============================================================================
extern "C" void kernel_launch(void* const* d_in, const int* in_sizes, int n_in,
                              void* d_out, int out_size, void* d_ws, size_t ws_size,
                              hipStream_t stream)
{
    (void)in_sizes; (void)n_in; (void)out_size; (void)ws_size;
    const float* x       = (const float*)d_in[0];
    const float* ln_g    = (const float*)d_in[1];
    const float* ln_b    = (const float*)d_in[2];
    const float* p1_w    = (const float*)d_in[3];
    const float* p1_b    = (const float*)d_in[4];
    const float* p2in_w  = (const float*)d_in[5];
    const float* p2in_b  = (const float*)d_in[6];
    const float* dw_w    = (const float*)d_in[7];
    const float* dw_b    = (const float*)d_in[8];
    const float* xproj_w = (const float*)d_in[9];
    const float* dtproj_w= (const float*)d_in[10];
    const float* dtproj_b= (const float*)d_in[11];
    const float* A_logs  = (const float*)d_in[12];
    const float* Ds      = (const float*)d_in[13];
    const float* ssln_g  = (const float*)d_in[14];
    const float* ssln_b  = (const float*)d_in[15];
    const float* p2n_g   = (const float*)d_in[16];
    const float* p2n_b   = (const float*)d_in[17];
    const float* ca_w1   = (const float*)d_in[18];
    const float* ca_b1   = (const float*)d_in[19];
    const float* ca_w2   = (const float*)d_in[20];
    const float* ca_b2   = (const float*)d_in[21];
    const int*  bidx     = (const int*)d_in[22];
    float* out = (float*)d_out;

    char* ws = (char*)d_ws;
    // element count per (q,b,c,l) tensor: 4*16*96*2304 = 14,155,776
    const size_t off_a    = 0;                                  // bf16, 28,311,552 B
    const size_t off_zt   = 28311552;                           // bf16
    const size_t off_ztT  = 56623104;                           // bf16
    const size_t off_xdbl = 84934656;                           // bf16, 25,952,256 B
    const size_t off_ys   = 110886912;                          // bf16, 113,246,208 B
    const size_t off_z0   = off_ys;                             // fp32 alias (dead before ys written)
    const size_t off_y    = off_zt;                             // bf16 alias (zt dead after scan)
    const size_t off_s    = 224133120;                          // fp32, 24,576 B
    const size_t off_att  = off_s + 24576;                      // fp32, 24,576 B

    bf16*  a_buf   = (bf16*)(ws + off_a);
    bf16*  zt_buf  = (bf16*)(ws + off_zt);
    bf16*  ztT_buf = (bf16*)(ws + off_ztT);
    bf16*  xdbl_buf= (bf16*)(ws + off_xdbl);
    bf16*  ys_buf  = (bf16*)(ws + off_ys);
    float* z0_buf  = (float*)(ws + off_z0);
    bf16*  y_buf   = (bf16*)(ws + off_y);
    float* s_buf   = (float*)(ws + off_s);
    float* att_buf = (float*)(ws + off_att);

    hipMemsetAsync(ws + off_s, 0, 24576, stream);

    k_lnconv<<<dim3(24, 16, 4), 192, 0, stream>>>(
        x, ln_g, ln_b, p1_w, p1_b, p2in_w, p2in_b, a_buf, z0_buf);
    k_dwconv<<<dim3(96, 16, 4), 256, 0, stream>>>(
        z0_buf, dw_w, dw_b, bidx, zt_buf, ztT_buf);
    k_xdbl<<<dim3(12, 4, 64), 256, 0, stream>>>(
        zt_buf, ztT_buf, xproj_w, xdbl_buf);
    k_scan<<<dim3(256), 384, 0, stream>>>(
        zt_buf, ztT_buf, xdbl_buf, dtproj_w, dtproj_b, A_logs, Ds, ys_buf);
    k_combine<<<dim3(48, 16, 4), 256, 0, stream>>>(
        ys_buf, a_buf, ssln_g, ssln_b, p2n_g, p2n_b, bidx, y_buf, s_buf);
    k_attn<<<dim3(16, 4), 128, 0, stream>>>(
        s_buf, ca_w1, ca_b1, ca_w2, ca_b2, att_buf);
    k_final<<<dim3(96, 16, 4), 256, 0, stream>>>(
        x, y_buf, att_buf, out);
}

// Round 4
// 881.502 us; speedup vs baseline: 1.5335x; 1.5335x over previous
//
#include <hip/hip_runtime.h>
#include <hip/hip_bf16.h>

// ---- problem constants ----
#define BQ 16      // batch
#define CN 96      // channels
#define HQ 48      // quadrant H = W
#define LL 2304    // HQ*HQ
#define NK 4       // scan directions
#define RR 6       // dt rank
#define NNS 8      // state size
#define DPJ 22     // R + 2N
#define CRr 12     // attention rank

using bf16 = __hip_bfloat16;

__device__ __forceinline__ float b2f(bf16 v) { return __bfloat162float(v); }
__device__ __forceinline__ bf16  f2b(float v){ return __float2bfloat16(v); }
__device__ __forceinline__ float bflo(unsigned u){ return __uint_as_float(u << 16); }
__device__ __forceinline__ float bfhi(unsigned u){ return __uint_as_float(u & 0xffff0000u); }
__device__ __forceinline__ float sigf(float x){ return 1.f / (1.f + __expf(-x)); }
__device__ __forceinline__ float siluf(float x){ return x / (1.f + __expf(-x)); }
__device__ __forceinline__ unsigned packbf(float a, float b){
    unsigned lo = (unsigned)__builtin_bit_cast(unsigned short, f2b(a));
    unsigned hi = (unsigned)__builtin_bit_cast(unsigned short, f2b(b));
    return lo | (hi << 16);
}
__device__ __forceinline__ unsigned rot16(unsigned u){ return (u >> 16) | (u << 16); }
__device__ __forceinline__ void unpack8(uint4 v, float* f){
    f[0]=bflo(v.x); f[1]=bfhi(v.x); f[2]=bflo(v.y); f[3]=bfhi(v.y);
    f[4]=bflo(v.z); f[5]=bfhi(v.z); f[6]=bflo(v.w); f[7]=bfhi(v.w);
}
// quad_perm DPP xor within groups of 4 lanes (VALU pipe, no LDS)
__device__ __forceinline__ float qxor(float v, int ctrl_b1){
    int x;
    if (ctrl_b1) x = __builtin_amdgcn_mov_dpp(__float_as_int(v), 0xB1, 0xF, 0xF, true);
    else         x = __builtin_amdgcn_mov_dpp(__float_as_int(v), 0x4E, 0xF, 0xF, true);
    return __int_as_float(x);
}

// ============================================================================
// K1: channel LN + conv1x1 (a-branch with silu, z-branch raw)
// grid (24, 16, 4) = (hh-pair, b, q), block 192
// ============================================================================
__global__ __launch_bounds__(192) void k_lnconv(
    const float* __restrict__ x, const float* __restrict__ ln_g, const float* __restrict__ ln_b,
    const float* __restrict__ p1w, const float* __restrict__ p1b,
    const float* __restrict__ p2w, const float* __restrict__ p2b,
    bf16* __restrict__ a_out, float* __restrict__ z0_out)
{
    const int hh2 = blockIdx.x;           // 0..23 (covers 2 rows each)
    const int b = blockIdx.y, q = blockIdx.z;
    const int h0 = (q >> 1) * HQ, w0 = (q & 1) * HQ;
    const int tid = threadIdx.x;
    const int qb = q * BQ + b;

    __shared__ alignas(16) bf16 hn[CN * 96];    // [c][p], p = local pos 0..95 (2 rows x 48)
    __shared__ alignas(16) bf16 wl[CN * 200];   // [c][row 0..191, pad to 200]
    __shared__ float mu[96], rs[96];

    // stage weights transposed: wl[c][d] = p1, wl[c][96+d] = p2in
    for (int t = tid; t < CN * CN; t += 192) {
        int d = t / CN, c = t % CN;
        wl[c * 200 + d]      = f2b(p1w[(q * CN + d) * CN + c]);
        wl[c * 200 + 96 + d] = f2b(p2w[(q * CN + d) * CN + c]);
    }
    // stage x tile: float4 loads, packed uint2 LDS writes
    for (int t = tid; t < CN * 24; t += 192) {
        int c = t / 24, v = t % 24;
        int row = v / 12, col = (v % 12) * 4;
        float4 xv = *reinterpret_cast<const float4*>(
            &x[((b * CN + c) * 96 + h0 + 2 * hh2 + row) * 96 + w0 + col]);
        uint2 pk; pk.x = packbf(xv.x, xv.y); pk.y = packbf(xv.z, xv.w);
        *reinterpret_cast<uint2*>(&hn[c * 96 + v * 4]) = pk;
    }
    __syncthreads();
    // LN stats per position
    if (tid < 96) {
        float s = 0.f, s2 = 0.f;
        for (int c = 0; c < CN; ++c) { float v = b2f(hn[c * 96 + tid]); s += v; s2 += v * v; }
        float m = s * (1.f / 96.f);
        float var = s2 * (1.f / 96.f) - m * m;
        mu[tid] = m; rs[tid] = rsqrtf(var + 1e-6f);
    }
    __syncthreads();
    // normalize in place
    for (int t = tid; t < CN * 96; t += 192) {
        int c = t / 96, p = t % 96;
        float g = ln_g[q * CN + c], bb = ln_b[q * CN + c];
        hn[t] = f2b((b2f(hn[t]) - mu[p]) * rs[p] * g + bb);
    }
    __syncthreads();
    // matvec: thread -> 8 output rows x 12 positions
    const int rg = tid >> 3, pg = tid & 7;
    const int row0 = rg * 8, pp0 = pg * 12;
    float acc[8][12];
    #pragma unroll
    for (int i = 0; i < 8; ++i)
        #pragma unroll
        for (int j = 0; j < 12; ++j) acc[i][j] = 0.f;

    for (int c = 0; c < CN; ++c) {
        uint4 wv = *reinterpret_cast<const uint4*>(&wl[c * 200 + row0]);
        float w[8];
        w[0] = bflo(wv.x); w[1] = bfhi(wv.x);
        w[2] = bflo(wv.y); w[3] = bfhi(wv.y);
        w[4] = bflo(wv.z); w[5] = bfhi(wv.z);
        w[6] = bflo(wv.w); w[7] = bfhi(wv.w);
        uint2 ha = *reinterpret_cast<const uint2*>(&hn[c * 96 + pp0]);
        uint2 hb = *reinterpret_cast<const uint2*>(&hn[c * 96 + pp0 + 4]);
        uint2 hc = *reinterpret_cast<const uint2*>(&hn[c * 96 + pp0 + 8]);
        float hv[12];
        hv[0] = bflo(ha.x); hv[1] = bfhi(ha.x); hv[2]  = bflo(ha.y); hv[3]  = bfhi(ha.y);
        hv[4] = bflo(hb.x); hv[5] = bfhi(hb.x); hv[6]  = bflo(hb.y); hv[7]  = bfhi(hb.y);
        hv[8] = bflo(hc.x); hv[9] = bfhi(hc.x); hv[10] = bflo(hc.y); hv[11] = bfhi(hc.y);
        #pragma unroll
        for (int i = 0; i < 8; ++i)
            #pragma unroll
            for (int j = 0; j < 12; ++j)
                acc[i][j] = fmaf(w[i], hv[j], acc[i][j]);
    }
    // epilogue: packed stores (12 contiguous elems per row)
    const int lbase = (2 * hh2 + pp0 / 48) * 48 + (pp0 % 48);
    #pragma unroll
    for (int i = 0; i < 8; ++i) {
        int row = row0 + i;
        bool isA = row < 96;
        int d = isA ? row : row - 96;
        float bias = isA ? p1b[q * CN + d] : p2b[q * CN + d];
        int oidx = (qb * CN + d) * LL + lbase;
        if (isA) {
            uint2 w0p, w1p, w2p;
            w0p.x = packbf(siluf(acc[i][0] + bias),  siluf(acc[i][1] + bias));
            w0p.y = packbf(siluf(acc[i][2] + bias),  siluf(acc[i][3] + bias));
            w1p.x = packbf(siluf(acc[i][4] + bias),  siluf(acc[i][5] + bias));
            w1p.y = packbf(siluf(acc[i][6] + bias),  siluf(acc[i][7] + bias));
            w2p.x = packbf(siluf(acc[i][8] + bias),  siluf(acc[i][9] + bias));
            w2p.y = packbf(siluf(acc[i][10] + bias), siluf(acc[i][11] + bias));
            *reinterpret_cast<uint2*>(&a_out[oidx])     = w0p;
            *reinterpret_cast<uint2*>(&a_out[oidx + 4]) = w1p;
            *reinterpret_cast<uint2*>(&a_out[oidx + 8]) = w2p;
        } else {
            float4 f0 = {acc[i][0]+bias, acc[i][1]+bias, acc[i][2]+bias, acc[i][3]+bias};
            float4 f1 = {acc[i][4]+bias, acc[i][5]+bias, acc[i][6]+bias, acc[i][7]+bias};
            float4 f2 = {acc[i][8]+bias, acc[i][9]+bias, acc[i][10]+bias, acc[i][11]+bias};
            *reinterpret_cast<float4*>(&z0_out[oidx])     = f0;
            *reinterpret_cast<float4*>(&z0_out[oidx + 4]) = f1;
            *reinterpret_cast<float4*>(&z0_out[oidx + 8]) = f2;
        }
    }
}

// ============================================================================
// K2: depthwise 3x3 SAME + bias + silu + block_idx transform
// grid (96, 16, 4) = (c, b, q), block 256
// ============================================================================
__global__ __launch_bounds__(256) void k_dwconv(
    const float* __restrict__ z0, const float* __restrict__ dww, const float* __restrict__ dwb,
    const int* __restrict__ bidx, bf16* __restrict__ zt, bf16* __restrict__ ztT)
{
    const int c = blockIdx.x, b = blockIdx.y, q = blockIdx.z;
    const int tid = threadIdx.x;
    const int base = ((q * BQ + b) * CN + c) * LL;
    __shared__ float zin[LL];
    __shared__ float zo[48 * 49];   // padded rows: conflict-free transposed reads
    for (int t = tid; t < LL / 4; t += 256)
        *reinterpret_cast<float4*>(&zin[t * 4]) =
            *reinterpret_cast<const float4*>(&z0[base + t * 4]);
    float wk[9];
    #pragma unroll
    for (int i = 0; i < 9; ++i) wk[i] = dww[(q * CN + c) * 9 + i];
    const float bias = dwb[q * CN + c];
    __syncthreads();
    for (int t = tid; t < LL; t += 256) {
        int hh = t / 48, ww = t % 48;
        float s = bias;
        #pragma unroll
        for (int dy = -1; dy <= 1; ++dy)
            #pragma unroll
            for (int dx = -1; dx <= 1; ++dx) {
                int yy = hh + dy, xx = ww + dx;
                if (yy >= 0 && yy < 48 && xx >= 0 && xx < 48)
                    s = fmaf(wk[(dy + 1) * 3 + (dx + 1)], zin[yy * 48 + xx], s);
            }
        zo[hh * 49 + ww] = siluf(s);
    }
    __syncthreads();
    const bool even = ((bidx[0] & 1) == 0);
    for (int t = tid; t < LL; t += 256) {
        int i = t / 48, j = t % 48;
        float vz, vzT;
        if (even) { vz = zo[j * 49 + i];               vzT = zo[i * 49 + j]; }
        else      { vz = zo[(47 - i) * 49 + (47 - j)]; vzT = zo[(47 - j) * 49 + (47 - i)]; }
        zt[base + t]  = f2b(vz);
        ztT[base + t] = f2b(vzT);
    }
}

// ============================================================================
// K3: x_dbl = xproj_w @ u_k  (direction mapping + reversal folded in)
// grid (12, 4, 64) = (l-tile, k, q*16+b), block 256
// ============================================================================
__global__ __launch_bounds__(256) void k_xdbl(
    const bf16* __restrict__ zt, const bf16* __restrict__ ztT,
    const float* __restrict__ xprojw, bf16* __restrict__ xdbl)
{
    const int lt = blockIdx.x, k = blockIdx.y, qb = blockIdx.z;
    const int tid = threadIdx.x;
    const int l0 = lt * 192;
    const int q = qb >> 4;
    __shared__ alignas(16) bf16 ul[CN * 200];
    __shared__ alignas(16) bf16 wl[DPJ * CN];
    const bf16* __restrict__ src = (k & 1) ? ztT : zt;
    const bool rev = (k >= 2);
    // vectorized staging: 96c x 24 vectors of 8 bf16
    for (int t = tid; t < CN * 24; t += 256) {
        int cc = t / 24, j0 = (t % 24) * 8;
        uint4 v;
        if (!rev) {
            v = *reinterpret_cast<const uint4*>(&src[(size_t)(qb * CN + cc) * LL + l0 + j0]);
        } else {
            v = *reinterpret_cast<const uint4*>(&src[(size_t)(qb * CN + cc) * LL + (LL - (l0 + j0) - 8)]);
            uint4 r; r.x = rot16(v.w); r.y = rot16(v.z); r.z = rot16(v.y); r.w = rot16(v.x);
            v = r;
        }
        *reinterpret_cast<uint4*>(&ul[cc * 200 + j0]) = v;
    }
    for (int t = tid; t < DPJ * CN; t += 256)
        wl[t] = f2b(xprojw[(q * NK + k) * DPJ * CN + t]);
    __syncthreads();
    // tiles: 2 d-rows x 8 l : 11 * 24 = 264 tiles
    for (int t = tid; t < 264; t += 256) {
        int dp = t / 24, lg = t % 24;
        int d0 = dp * 2, llp = lg * 8;
        float acc0[8], acc1[8];
        #pragma unroll
        for (int j = 0; j < 8; ++j) { acc0[j] = 0.f; acc1[j] = 0.f; }
        for (int c = 0; c < CN; ++c) {
            float w0 = b2f(wl[d0 * CN + c]);
            float w1 = b2f(wl[(d0 + 1) * CN + c]);
            uint4 uv = *reinterpret_cast<const uint4*>(&ul[c * 200 + llp]);
            float uf[8];
            unpack8(uv, uf);
            #pragma unroll
            for (int j = 0; j < 8; ++j) {
                acc0[j] = fmaf(w0, uf[j], acc0[j]);
                acc1[j] = fmaf(w1, uf[j], acc1[j]);
            }
        }
        int ob = (qb * NK + k) * DPJ * LL + l0 + llp;
        uint4 o0, o1;
        o0.x = packbf(acc0[0], acc0[1]); o0.y = packbf(acc0[2], acc0[3]);
        o0.z = packbf(acc0[4], acc0[5]); o0.w = packbf(acc0[6], acc0[7]);
        o1.x = packbf(acc1[0], acc1[1]); o1.y = packbf(acc1[2], acc1[3]);
        o1.z = packbf(acc1[4], acc1[5]); o1.w = packbf(acc1[6], acc1[7]);
        *reinterpret_cast<uint4*>(&xdbl[ob + d0 * LL])       = o0;
        *reinterpret_cast<uint4*>(&xdbl[ob + (d0 + 1) * LL]) = o1;
    }
}

// ============================================================================
// K4: fused delta(softplus) + selective scan + Ds*u term
// grid (256) = (qb,k), block 384 = 96 c x 4 lanes (2 states each)
// vectorized double-buffered staging, DPP quad reduce, register y-pack
// ============================================================================
__global__ __launch_bounds__(384) void k_scan(
    const bf16* __restrict__ zt, const bf16* __restrict__ ztT,
    const bf16* __restrict__ xdbl,
    const float* __restrict__ dtw_g, const float* __restrict__ dtb_g,
    const float* __restrict__ Alog_g, const float* __restrict__ Ds_g,
    bf16* __restrict__ ys)
{
    const int bid = blockIdx.x;
    const int k = bid & 3, qb = bid >> 2, q = qb >> 4, qk = q * NK + k;
    const int tid = threadIdx.x;
    const int c = tid >> 2, p = tid & 3, n0 = 2 * p;

    __shared__ float2 ud[CN * 50];   // (u, delta)[c][j], pad 50
    __shared__ float  xr[DPJ * 52];  // xdbl rows [v][j], pad 52 (0-5 dts, 6-13 B, 14-21 C)
    __shared__ float  wdt[CN * RR];
    __shared__ float  dtb[CN];

    for (int t = tid; t < CN * RR; t += 384) wdt[t] = dtw_g[qk * CN * RR + t];
    if (tid < CN) dtb[tid] = dtb_g[qk * CN + tid];

    const float A0 = -__expf(Alog_g[(qk * CN + c) * NNS + n0]);
    const float A1 = -__expf(Alog_g[(qk * CN + c) * NNS + n0 + 1]);
    const float Dc = Ds_g[qk * CN + c];
    float h0 = 0.f, h1 = 0.f;

    const bf16* __restrict__ src = (k & 1) ? ztT : zt;
    const bool rev = (k >= 2);
    const size_t ubase = (size_t)qb * (CN * LL);
    const size_t xbase = (size_t)(qb * NK + k) * (DPJ * LL);
    const size_t ybase = (size_t)(qb * NK + k) * (CN * LL);

    // staging roles (addresses hoisted out of the chunk loop)
    const int ca = tid / 6,          ja = (tid % 6) * 8;            // u vec A (all threads)
    const int cb = (tid + 384) / 6,  jb2 = ((tid + 384) % 6) * 8;   // u vec B (tid<192)
    const bool xload = (tid >= 192 && tid < 324);
    const int xv = tid - 192;
    const int vr = xv / 6, jx = (xv % 6) * 8;                       // xr vec
    const int ustep = rev ? -48 : 48;

    const bf16* gpa = src + ubase + (size_t)ca * LL + (rev ? (LL - 8 - ja)  : ja);
    const bf16* gpb = src + ubase + (size_t)cb * LL + (rev ? (LL - 8 - jb2) : jb2);
    const bf16* gpx = xdbl + xbase + (size_t)vr * LL + jx;

    // delta role: fixed column jj, rows cc0 + 8i
    const int jj = tid % 48, cc0 = tid / 48;

    bf16* yp = ys + ybase + (size_t)c * LL;    // p==0 lanes store

    uint4 pfa = *reinterpret_cast<const uint4*>(gpa);
    uint4 pfb = {0,0,0,0}, pfx = {0,0,0,0};
    if (tid < 192) pfb = *reinterpret_cast<const uint4*>(gpb);
    if (xload)     pfx = *reinterpret_cast<const uint4*>(gpx);

    for (int ch = 0; ch < 48; ++ch) {
        __syncthreads();    // previous chunk's LDS reads complete
        // commit staged regs to LDS (reversal via index select, fully unrolled)
        {
            float f[8]; unpack8(pfa, f);
            float2* udp = &ud[ca * 50 + ja];
            #pragma unroll
            for (int i = 0; i < 8; ++i) {
                int ii = rev ? (7 - i) : i;
                udp[i].x = f[ii];
            }
        }
        if (tid < 192) {
            float f[8]; unpack8(pfb, f);
            float2* udp = &ud[cb * 50 + jb2];
            #pragma unroll
            for (int i = 0; i < 8; ++i) {
                int ii = rev ? (7 - i) : i;
                udp[i].x = f[ii];
            }
        }
        if (xload) {
            float f[8]; unpack8(pfx, f);
            float4 lo = {f[0], f[1], f[2], f[3]}, hi = {f[4], f[5], f[6], f[7]};
            *reinterpret_cast<float4*>(&xr[vr * 52 + jx])     = lo;
            *reinterpret_cast<float4*>(&xr[vr * 52 + jx + 4]) = hi;
        }
        __syncthreads();
        // prefetch next chunk (overlaps delta + scan)
        if (ch < 47) {
            gpa += ustep; pfa = *reinterpret_cast<const uint4*>(gpa);
            if (tid < 192) { gpb += ustep; pfb = *reinterpret_cast<const uint4*>(gpb); }
            if (xload)     { gpx += 48;    pfx = *reinterpret_cast<const uint4*>(gpx); }
        }
        // delta = softplus(wdt . dts + dtb): 12 channels per thread, shared dts reads
        {
            float dt0 = xr[0 * 52 + jj], dt1 = xr[1 * 52 + jj], dt2 = xr[2 * 52 + jj];
            float dt3 = xr[3 * 52 + jj], dt4 = xr[4 * 52 + jj], dt5 = xr[5 * 52 + jj];
            #pragma unroll
            for (int i = 0; i < 12; ++i) {
                int cc = cc0 + 8 * i;
                float a = dtb[cc];
                a = fmaf(wdt[cc * 6 + 0], dt0, a);
                a = fmaf(wdt[cc * 6 + 1], dt1, a);
                a = fmaf(wdt[cc * 6 + 2], dt2, a);
                a = fmaf(wdt[cc * 6 + 3], dt3, a);
                a = fmaf(wdt[cc * 6 + 4], dt4, a);
                a = fmaf(wdt[cc * 6 + 5], dt5, a);
                a = (a > 15.f) ? a : __logf(1.f + __expf(a));
                ud[cc * 50 + jj].y = a;
            }
        }
        __syncthreads();
        // scan 48 steps; pack 8 outputs -> one uint4 store (p==0 lanes)
        const int l0 = ch * 48;
        #pragma unroll
        for (int g = 0; g < 6; ++g) {
            unsigned pk[4];
            #pragma unroll
            for (int j2 = 0; j2 < 8; ++j2) {
                const int j = g * 8 + j2;
                float2 f = ud[c * 50 + j];
                float u = f.x, d = f.y;
                float du = d * u;
                float B0 = xr[(6 + n0) * 52 + j],  B1 = xr[(7 + n0) * 52 + j];
                float C0 = xr[(14 + n0) * 52 + j], C1 = xr[(15 + n0) * 52 + j];
                float dA0 = __expf(d * A0), dA1 = __expf(d * A1);
                h0 = fmaf(dA0, h0, du * B0);
                h1 = fmaf(dA1, h1, du * B1);
                float y = fmaf(h0, C0, h1 * C1);
                y += qxor(y, 1);
                y += qxor(y, 0);
                y = fmaf(Dc, u, y);
                unsigned hb = (unsigned)__builtin_bit_cast(unsigned short, f2b(y));
                if (j2 & 1) pk[j2 >> 1] |= hb << 16; else pk[j2 >> 1] = hb;
            }
            if (p == 0) {
                uint4 w; w.x = pk[0]; w.y = pk[1]; w.z = pk[2]; w.w = pk[3];
                *reinterpret_cast<uint4*>(yp + l0 + g * 8) = w;
            }
        }
    }
}

// ============================================================================
// K5: combine 4 directions + LN(ssln) + inverse transform + LN(p2n) + y=a*z
// grid (48, 16, 4) = (ww', b, q), block 256
// ============================================================================
__global__ __launch_bounds__(256) void k_combine(
    const bf16* __restrict__ ys, const bf16* __restrict__ a_in,
    const float* __restrict__ ssg, const float* __restrict__ ssb,
    const float* __restrict__ png, const float* __restrict__ pnb,
    const int* __restrict__ bidx,
    bf16* __restrict__ y_out, float* __restrict__ s_buf)
{
    const int ww = blockIdx.x, b = blockIdx.y, q = blockIdx.z;
    const int qb = q * BQ + b;
    const int tid = threadIdx.x;
    __shared__ float o[CN * 48];
    __shared__ float mu[48], rs[48];
    const size_t ysb = (size_t)qb * NK * CN * LL;
    for (int t = tid; t < CN * 48; t += 256) {
        int c = t / 48, hh = t % 48;
        float v0 = b2f(ys[ysb + (size_t)(0 * CN + c) * LL + hh * 48 + ww]);
        float v1 = b2f(ys[ysb + (size_t)(1 * CN + c) * LL + ww * 48 + hh]);
        float v2 = b2f(ys[ysb + (size_t)(2 * CN + c) * LL + (LL - 1) - hh * 48 - ww]);
        float v3 = b2f(ys[ysb + (size_t)(3 * CN + c) * LL + (LL - 1) - ww * 48 - hh]);
        o[t] = v0 + v1 + v2 + v3;
    }
    __syncthreads();
    if (tid < 48) {
        float s = 0.f, s2 = 0.f;
        for (int cc = 0; cc < CN; ++cc) { float v = o[cc * 48 + tid]; s += v; s2 += v * v; }
        float m = s * (1.f / 96.f), var = s2 * (1.f / 96.f) - m * m;
        mu[tid] = m; rs[tid] = rsqrtf(var + 1e-6f);
    }
    __syncthreads();
    for (int t = tid; t < CN * 48; t += 256) {
        int cc = t / 48, hh = t % 48;
        o[t] = (o[t] - mu[hh]) * rs[hh] * ssg[q * CN + cc] + ssb[q * CN + cc];
    }
    __syncthreads();
    if (tid < 48) {
        float s = 0.f, s2 = 0.f;
        for (int cc = 0; cc < CN; ++cc) { float v = o[cc * 48 + tid]; s += v; s2 += v * v; }
        float m = s * (1.f / 96.f), var = s2 * (1.f / 96.f) - m * m;
        mu[tid] = m; rs[tid] = rsqrtf(var + 1e-6f);
    }
    __syncthreads();
    const bool even = ((bidx[0] & 1) == 0);
    for (int t = tid; t < CN * 48; t += 256) {
        int cc = t / 48, hh = t % 48;
        float z2 = (o[t] - mu[hh]) * rs[hh] * png[q * CN + cc] + pnb[q * CN + cc];
        int oidx;
        if (even) oidx = (qb * CN + cc) * LL + ww * 48 + hh;
        else      oidx = (qb * CN + cc) * LL + (47 - hh) * 48 + (47 - ww);
        float yv = b2f(a_in[oidx]) * z2;
        y_out[oidx] = f2b(yv);
        o[t] = yv;
    }
    __syncthreads();
    if (tid < CN) {
        float s = 0.f;
        for (int j = 0; j < 48; ++j) s += o[tid * 48 + j];
        atomicAdd(&s_buf[qb * CN + tid], s);
    }
}

// ============================================================================
// K6: channel attention
// grid (16, 4), block 128
// ============================================================================
__global__ __launch_bounds__(128) void k_attn(
    const float* __restrict__ s_buf,
    const float* __restrict__ w1, const float* __restrict__ b1,
    const float* __restrict__ w2, const float* __restrict__ b2,
    float* __restrict__ att)
{
    const int b = blockIdx.x, q = blockIdx.y;
    const int qb = q * BQ + b;
    const int tid = threadIdx.x;
    __shared__ float sm[CN], tl[CRr];
    if (tid < CN) sm[tid] = s_buf[qb * CN + tid] * (1.f / (float)LL);
    __syncthreads();
    if (tid < CRr) {
        float acc = b1[q * CRr + tid];
        for (int cc = 0; cc < CN; ++cc)
            acc = fmaf(w1[(q * CRr + tid) * CN + cc], sm[cc], acc);
        tl[tid] = siluf(acc);
    }
    __syncthreads();
    if (tid < CN) {
        float acc = b2[q * CN + tid];
        #pragma unroll
        for (int r = 0; r < CRr; ++r)
            acc = fmaf(w2[(q * CN + tid) * CRr + r], tl[r], acc);
        att[qb * CN + tid] = sigf(acc);
    }
}

// ============================================================================
// K7: out = x + y * att  (vectorized)
// grid (96, 16, 4) = (c, b, q), block 256
// ============================================================================
__global__ __launch_bounds__(256) void k_final(
    const float* __restrict__ x, const bf16* __restrict__ y_in,
    const float* __restrict__ att, float* __restrict__ out)
{
    const int c = blockIdx.x, b = blockIdx.y, q = blockIdx.z;
    const int h0 = (q >> 1) * HQ, w0 = (q & 1) * HQ;
    const int qb = q * BQ + b;
    const float av = att[qb * CN + c];
    const size_t ybase = (size_t)(qb * CN + c) * LL;
    const int xb = (b * CN + c) * 9216 + h0 * 96 + w0;
    for (int t = threadIdx.x; t < LL / 8; t += 256) {
        int e0 = t * 8;
        int gi = xb + (e0 / 48) * 96 + (e0 % 48);
        uint4 yv = *reinterpret_cast<const uint4*>(&y_in[ybase + e0]);
        float yf[8]; unpack8(yv, yf);
        float4 xa = *reinterpret_cast<const float4*>(&x[gi]);
        float4 xc = *reinterpret_cast<const float4*>(&x[gi + 4]);
        float4 o0 = {xa.x + yf[0]*av, xa.y + yf[1]*av, xa.z + yf[2]*av, xa.w + yf[3]*av};
        float4 o1 = {xc.x + yf[4]*av, xc.y + yf[5]*av, xc.z + yf[6]*av, xc.w + yf[7]*av};
        *reinterpret_cast<float4*>(&out[gi])     = o0;
        *reinterpret_cast<float4*>(&out[gi + 4]) = o1;
    }
}

// ============================================================================
extern "C" void kernel_launch(void* const* d_in, const int* in_sizes, int n_in,
                              void* d_out, int out_size, void* d_ws, size_t ws_size,
                              hipStream_t stream)
{
    (void)in_sizes; (void)n_in; (void)out_size; (void)ws_size;
    const float* x       = (const float*)d_in[0];
    const float* ln_g    = (const float*)d_in[1];
    const float* ln_b    = (const float*)d_in[2];
    const float* p1_w    = (const float*)d_in[3];
    const float* p1_b    = (const float*)d_in[4];
    const float* p2in_w  = (const float*)d_in[5];
    const float* p2in_b  = (const float*)d_in[6];
    const float* dw_w    = (const float*)d_in[7];
    const float* dw_b    = (const float*)d_in[8];
    const float* xproj_w = (const float*)d_in[9];
    const float* dtproj_w= (const float*)d_in[10];
    const float* dtproj_b= (const float*)d_in[11];
    const float* A_logs  = (const float*)d_in[12];
    const float* Ds      = (const float*)d_in[13];
    const float* ssln_g  = (const float*)d_in[14];
    const float* ssln_b  = (const float*)d_in[15];
    const float* p2n_g   = (const float*)d_in[16];
    const float* p2n_b   = (const float*)d_in[17];
    const float* ca_w1   = (const float*)d_in[18];
    const float* ca_b1   = (const float*)d_in[19];
    const float* ca_w2   = (const float*)d_in[20];
    const float* ca_b2   = (const float*)d_in[21];
    const int*  bidx     = (const int*)d_in[22];
    float* out = (float*)d_out;

    char* ws = (char*)d_ws;
    const size_t off_a    = 0;                                  // bf16
    const size_t off_zt   = 28311552;                           // bf16
    const size_t off_ztT  = 56623104;                           // bf16
    const size_t off_xdbl = 84934656;                           // bf16
    const size_t off_ys   = 110886912;                          // bf16
    const size_t off_z0   = off_ys;                             // fp32 alias
    const size_t off_y    = off_zt;                             // bf16 alias
    const size_t off_s    = 224133120;                          // fp32
    const size_t off_att  = off_s + 24576;                      // fp32

    bf16*  a_buf   = (bf16*)(ws + off_a);
    bf16*  zt_buf  = (bf16*)(ws + off_zt);
    bf16*  ztT_buf = (bf16*)(ws + off_ztT);
    bf16*  xdbl_buf= (bf16*)(ws + off_xdbl);
    bf16*  ys_buf  = (bf16*)(ws + off_ys);
    float* z0_buf  = (float*)(ws + off_z0);
    bf16*  y_buf   = (bf16*)(ws + off_y);
    float* s_buf   = (float*)(ws + off_s);
    float* att_buf = (float*)(ws + off_att);

    (void)hipMemsetAsync(ws + off_s, 0, 24576, stream);

    k_lnconv<<<dim3(24, 16, 4), 192, 0, stream>>>(
        x, ln_g, ln_b, p1_w, p1_b, p2in_w, p2in_b, a_buf, z0_buf);
    k_dwconv<<<dim3(96, 16, 4), 256, 0, stream>>>(
        z0_buf, dw_w, dw_b, bidx, zt_buf, ztT_buf);
    k_xdbl<<<dim3(12, 4, 64), 256, 0, stream>>>(
        zt_buf, ztT_buf, xproj_w, xdbl_buf);
    k_scan<<<dim3(256), 384, 0, stream>>>(
        zt_buf, ztT_buf, xdbl_buf, dtproj_w, dtproj_b, A_logs, Ds, ys_buf);
    k_combine<<<dim3(48, 16, 4), 256, 0, stream>>>(
        ys_buf, a_buf, ssln_g, ssln_b, p2n_g, p2n_b, bidx, y_buf, s_buf);
    k_attn<<<dim3(16, 4), 128, 0, stream>>>(
        s_buf, ca_w1, ca_b1, ca_w2, ca_b2, att_buf);
    k_final<<<dim3(96, 16, 4), 256, 0, stream>>>(
        x, y_buf, att_buf, out);
}

// Round 5
// 771.462 us; speedup vs baseline: 1.7523x; 1.1426x over previous
//
#include <hip/hip_runtime.h>
#include <hip/hip_bf16.h>

// ---- problem constants ----
#define BQ 16      // batch
#define CN 96      // channels
#define HQ 48      // quadrant H = W
#define LL 2304    // HQ*HQ
#define NK 4       // scan directions
#define RR 6       // dt rank
#define NNS 8      // state size
#define DPJ 22     // R + 2N
#define CRr 12     // attention rank

using bf16 = __hip_bfloat16;

__device__ __forceinline__ float b2f(bf16 v) { return __bfloat162float(v); }
__device__ __forceinline__ bf16  f2b(float v){ return __float2bfloat16(v); }
__device__ __forceinline__ float bflo(unsigned u){ return __uint_as_float(u << 16); }
__device__ __forceinline__ float bfhi(unsigned u){ return __uint_as_float(u & 0xffff0000u); }
__device__ __forceinline__ float sigf(float x){ return 1.f / (1.f + __expf(-x)); }
__device__ __forceinline__ float siluf(float x){ return x / (1.f + __expf(-x)); }
__device__ __forceinline__ unsigned packbf(float a, float b){
    unsigned lo = (unsigned)__builtin_bit_cast(unsigned short, f2b(a));
    unsigned hi = (unsigned)__builtin_bit_cast(unsigned short, f2b(b));
    return lo | (hi << 16);
}
__device__ __forceinline__ unsigned rot16(unsigned u){ return (u >> 16) | (u << 16); }
__device__ __forceinline__ void unpack8(uint4 v, float* f){
    f[0]=bflo(v.x); f[1]=bfhi(v.x); f[2]=bflo(v.y); f[3]=bfhi(v.y);
    f[4]=bflo(v.z); f[5]=bfhi(v.z); f[6]=bflo(v.w); f[7]=bfhi(v.w);
}
__device__ __forceinline__ void unpack4(uint2 v, float* f){
    f[0]=bflo(v.x); f[1]=bfhi(v.x); f[2]=bflo(v.y); f[3]=bfhi(v.y);
}
// quad_perm DPP xor within groups of 4 lanes (VALU pipe, no LDS)
__device__ __forceinline__ float qxor(float v, int ctrl_b1){
    int x;
    if (ctrl_b1) x = __builtin_amdgcn_mov_dpp(__float_as_int(v), 0xB1, 0xF, 0xF, true);
    else         x = __builtin_amdgcn_mov_dpp(__float_as_int(v), 0x4E, 0xF, 0xF, true);
    return __int_as_float(x);
}

// ============================================================================
// K1: channel LN + conv1x1 (a-branch with silu, z-branch raw)
// grid (24, 16, 4) = (hh-pair, b, q), block 192
// ============================================================================
__global__ __launch_bounds__(192) void k_lnconv(
    const float* __restrict__ x, const float* __restrict__ ln_g, const float* __restrict__ ln_b,
    const float* __restrict__ p1w, const float* __restrict__ p1b,
    const float* __restrict__ p2w, const float* __restrict__ p2b,
    bf16* __restrict__ a_out, float* __restrict__ z0_out)
{
    const int hh2 = blockIdx.x;           // 0..23 (covers 2 rows each)
    const int b = blockIdx.y, q = blockIdx.z;
    const int h0 = (q >> 1) * HQ, w0 = (q & 1) * HQ;
    const int tid = threadIdx.x;
    const int qb = q * BQ + b;

    __shared__ alignas(16) bf16 hn[CN * 96];    // [c][p], p = local pos 0..95 (2 rows x 48)
    __shared__ alignas(16) bf16 wl[CN * 200];   // [c][row 0..191, pad to 200]
    __shared__ float mu[96], rs[96];

    // stage weights transposed: wl[c][d] = p1, wl[c][96+d] = p2in
    for (int t = tid; t < CN * CN; t += 192) {
        int d = t / CN, c = t % CN;
        wl[c * 200 + d]      = f2b(p1w[(q * CN + d) * CN + c]);
        wl[c * 200 + 96 + d] = f2b(p2w[(q * CN + d) * CN + c]);
    }
    // stage x tile: float4 loads, packed uint2 LDS writes
    for (int t = tid; t < CN * 24; t += 192) {
        int c = t / 24, v = t % 24;
        int row = v / 12, col = (v % 12) * 4;
        float4 xv = *reinterpret_cast<const float4*>(
            &x[((b * CN + c) * 96 + h0 + 2 * hh2 + row) * 96 + w0 + col]);
        uint2 pk; pk.x = packbf(xv.x, xv.y); pk.y = packbf(xv.z, xv.w);
        *reinterpret_cast<uint2*>(&hn[c * 96 + v * 4]) = pk;
    }
    __syncthreads();
    // LN stats per position
    if (tid < 96) {
        float s = 0.f, s2 = 0.f;
        for (int c = 0; c < CN; ++c) { float v = b2f(hn[c * 96 + tid]); s += v; s2 += v * v; }
        float m = s * (1.f / 96.f);
        float var = s2 * (1.f / 96.f) - m * m;
        mu[tid] = m; rs[tid] = rsqrtf(var + 1e-6f);
    }
    __syncthreads();
    // normalize in place
    for (int t = tid; t < CN * 96; t += 192) {
        int c = t / 96, p = t % 96;
        float g = ln_g[q * CN + c], bb = ln_b[q * CN + c];
        hn[t] = f2b((b2f(hn[t]) - mu[p]) * rs[p] * g + bb);
    }
    __syncthreads();
    // matvec: thread -> 8 output rows x 12 positions
    const int rg = tid >> 3, pg = tid & 7;
    const int row0 = rg * 8, pp0 = pg * 12;
    float acc[8][12];
    #pragma unroll
    for (int i = 0; i < 8; ++i)
        #pragma unroll
        for (int j = 0; j < 12; ++j) acc[i][j] = 0.f;

    for (int c = 0; c < CN; ++c) {
        uint4 wv = *reinterpret_cast<const uint4*>(&wl[c * 200 + row0]);
        float w[8];
        w[0] = bflo(wv.x); w[1] = bfhi(wv.x);
        w[2] = bflo(wv.y); w[3] = bfhi(wv.y);
        w[4] = bflo(wv.z); w[5] = bfhi(wv.z);
        w[6] = bflo(wv.w); w[7] = bfhi(wv.w);
        uint2 ha = *reinterpret_cast<const uint2*>(&hn[c * 96 + pp0]);
        uint2 hb = *reinterpret_cast<const uint2*>(&hn[c * 96 + pp0 + 4]);
        uint2 hc = *reinterpret_cast<const uint2*>(&hn[c * 96 + pp0 + 8]);
        float hv[12];
        hv[0] = bflo(ha.x); hv[1] = bfhi(ha.x); hv[2]  = bflo(ha.y); hv[3]  = bfhi(ha.y);
        hv[4] = bflo(hb.x); hv[5] = bfhi(hb.x); hv[6]  = bflo(hb.y); hv[7]  = bfhi(hb.y);
        hv[8] = bflo(hc.x); hv[9] = bfhi(hc.x); hv[10] = bflo(hc.y); hv[11] = bfhi(hc.y);
        #pragma unroll
        for (int i = 0; i < 8; ++i)
            #pragma unroll
            for (int j = 0; j < 12; ++j)
                acc[i][j] = fmaf(w[i], hv[j], acc[i][j]);
    }
    // epilogue: packed stores (12 contiguous elems per row)
    const int lbase = (2 * hh2 + pp0 / 48) * 48 + (pp0 % 48);
    #pragma unroll
    for (int i = 0; i < 8; ++i) {
        int row = row0 + i;
        bool isA = row < 96;
        int d = isA ? row : row - 96;
        float bias = isA ? p1b[q * CN + d] : p2b[q * CN + d];
        int oidx = (qb * CN + d) * LL + lbase;
        if (isA) {
            uint2 w0p, w1p, w2p;
            w0p.x = packbf(siluf(acc[i][0] + bias),  siluf(acc[i][1] + bias));
            w0p.y = packbf(siluf(acc[i][2] + bias),  siluf(acc[i][3] + bias));
            w1p.x = packbf(siluf(acc[i][4] + bias),  siluf(acc[i][5] + bias));
            w1p.y = packbf(siluf(acc[i][6] + bias),  siluf(acc[i][7] + bias));
            w2p.x = packbf(siluf(acc[i][8] + bias),  siluf(acc[i][9] + bias));
            w2p.y = packbf(siluf(acc[i][10] + bias), siluf(acc[i][11] + bias));
            *reinterpret_cast<uint2*>(&a_out[oidx])     = w0p;
            *reinterpret_cast<uint2*>(&a_out[oidx + 4]) = w1p;
            *reinterpret_cast<uint2*>(&a_out[oidx + 8]) = w2p;
        } else {
            float4 f0 = {acc[i][0]+bias, acc[i][1]+bias, acc[i][2]+bias, acc[i][3]+bias};
            float4 f1 = {acc[i][4]+bias, acc[i][5]+bias, acc[i][6]+bias, acc[i][7]+bias};
            float4 f2 = {acc[i][8]+bias, acc[i][9]+bias, acc[i][10]+bias, acc[i][11]+bias};
            *reinterpret_cast<float4*>(&z0_out[oidx])     = f0;
            *reinterpret_cast<float4*>(&z0_out[oidx + 4]) = f1;
            *reinterpret_cast<float4*>(&z0_out[oidx + 8]) = f2;
        }
    }
}

// ============================================================================
// K2: depthwise 3x3 SAME + bias + silu + block_idx transform
// grid (96, 16, 4) = (c, b, q), block 256
// ============================================================================
__global__ __launch_bounds__(256) void k_dwconv(
    const float* __restrict__ z0, const float* __restrict__ dww, const float* __restrict__ dwb,
    const int* __restrict__ bidx, bf16* __restrict__ zt, bf16* __restrict__ ztT)
{
    const int c = blockIdx.x, b = blockIdx.y, q = blockIdx.z;
    const int tid = threadIdx.x;
    const int base = ((q * BQ + b) * CN + c) * LL;
    __shared__ float zin[LL];
    __shared__ float zo[48 * 49];   // padded rows: conflict-free transposed reads
    for (int t = tid; t < LL / 4; t += 256)
        *reinterpret_cast<float4*>(&zin[t * 4]) =
            *reinterpret_cast<const float4*>(&z0[base + t * 4]);
    float wk[9];
    #pragma unroll
    for (int i = 0; i < 9; ++i) wk[i] = dww[(q * CN + c) * 9 + i];
    const float bias = dwb[q * CN + c];
    __syncthreads();
    for (int t = tid; t < LL; t += 256) {
        int hh = t / 48, ww = t % 48;
        float s = bias;
        #pragma unroll
        for (int dy = -1; dy <= 1; ++dy)
            #pragma unroll
            for (int dx = -1; dx <= 1; ++dx) {
                int yy = hh + dy, xx = ww + dx;
                if (yy >= 0 && yy < 48 && xx >= 0 && xx < 48)
                    s = fmaf(wk[(dy + 1) * 3 + (dx + 1)], zin[yy * 48 + xx], s);
            }
        zo[hh * 49 + ww] = siluf(s);
    }
    __syncthreads();
    const bool even = ((bidx[0] & 1) == 0);
    for (int t = tid; t < LL; t += 256) {
        int i = t / 48, j = t % 48;
        float vz, vzT;
        if (even) { vz = zo[j * 49 + i];               vzT = zo[i * 49 + j]; }
        else      { vz = zo[(47 - i) * 49 + (47 - j)]; vzT = zo[(47 - j) * 49 + (47 - i)]; }
        zt[base + t]  = f2b(vz);
        ztT[base + t] = f2b(vzT);
    }
}

// ============================================================================
// K3: x_dbl = xproj_w @ u_k  (direction mapping + reversal folded in)
// grid (12, 4, 64) = (l-tile, k, q*16+b), block 256
// ============================================================================
__global__ __launch_bounds__(256) void k_xdbl(
    const bf16* __restrict__ zt, const bf16* __restrict__ ztT,
    const float* __restrict__ xprojw, bf16* __restrict__ xdbl)
{
    const int lt = blockIdx.x, k = blockIdx.y, qb = blockIdx.z;
    const int tid = threadIdx.x;
    const int l0 = lt * 192;
    const int q = qb >> 4;
    __shared__ alignas(16) bf16 ul[CN * 200];
    __shared__ alignas(16) bf16 wl[DPJ * CN];
    const bf16* __restrict__ src = (k & 1) ? ztT : zt;
    const bool rev = (k >= 2);
    // vectorized staging: 96c x 24 vectors of 8 bf16
    for (int t = tid; t < CN * 24; t += 256) {
        int cc = t / 24, j0 = (t % 24) * 8;
        uint4 v;
        if (!rev) {
            v = *reinterpret_cast<const uint4*>(&src[(size_t)(qb * CN + cc) * LL + l0 + j0]);
        } else {
            v = *reinterpret_cast<const uint4*>(&src[(size_t)(qb * CN + cc) * LL + (LL - (l0 + j0) - 8)]);
            uint4 r; r.x = rot16(v.w); r.y = rot16(v.z); r.z = rot16(v.y); r.w = rot16(v.x);
            v = r;
        }
        *reinterpret_cast<uint4*>(&ul[cc * 200 + j0]) = v;
    }
    for (int t = tid; t < DPJ * CN; t += 256)
        wl[t] = f2b(xprojw[(q * NK + k) * DPJ * CN + t]);
    __syncthreads();
    // tiles: 2 d-rows x 8 l : 11 * 24 = 264 tiles
    for (int t = tid; t < 264; t += 256) {
        int dp = t / 24, lg = t % 24;
        int d0 = dp * 2, llp = lg * 8;
        float acc0[8], acc1[8];
        #pragma unroll
        for (int j = 0; j < 8; ++j) { acc0[j] = 0.f; acc1[j] = 0.f; }
        for (int c = 0; c < CN; ++c) {
            float w0 = b2f(wl[d0 * CN + c]);
            float w1 = b2f(wl[(d0 + 1) * CN + c]);
            uint4 uv = *reinterpret_cast<const uint4*>(&ul[c * 200 + llp]);
            float uf[8];
            unpack8(uv, uf);
            #pragma unroll
            for (int j = 0; j < 8; ++j) {
                acc0[j] = fmaf(w0, uf[j], acc0[j]);
                acc1[j] = fmaf(w1, uf[j], acc1[j]);
            }
        }
        int ob = (qb * NK + k) * DPJ * LL + l0 + llp;
        uint4 o0, o1;
        o0.x = packbf(acc0[0], acc0[1]); o0.y = packbf(acc0[2], acc0[3]);
        o0.z = packbf(acc0[4], acc0[5]); o0.w = packbf(acc0[6], acc0[7]);
        o1.x = packbf(acc1[0], acc1[1]); o1.y = packbf(acc1[2], acc1[3]);
        o1.z = packbf(acc1[4], acc1[5]); o1.w = packbf(acc1[6], acc1[7]);
        *reinterpret_cast<uint4*>(&xdbl[ob + d0 * LL])       = o0;
        *reinterpret_cast<uint4*>(&xdbl[ob + (d0 + 1) * LL]) = o1;
    }
}

// ============================================================================
// K4: fused delta(softplus) + selective scan + Ds*u term
// grid (512) = (qb,k,chalf), block 192 = 48 c x 4 lanes (2 states each)
// 2 blocks/CU; separate uu/dd arrays (b128 staging, b64 paired reads);
// bc transposed [j][v] for b64 state-pair reads; wdt in registers.
// ============================================================================
__global__ __launch_bounds__(192) void k_scan(
    const bf16* __restrict__ zt, const bf16* __restrict__ ztT,
    const bf16* __restrict__ xdbl,
    const float* __restrict__ dtw_g, const float* __restrict__ dtb_g,
    const float* __restrict__ Alog_g, const float* __restrict__ Ds_g,
    bf16* __restrict__ ys)
{
    const int bid = blockIdx.x;
    const int ch2 = bid & 1, k = (bid >> 1) & 3, qb = bid >> 3, q = qb >> 4;
    const int qk = q * NK + k;
    const int tid = threadIdx.x;
    const int ca = tid >> 2, p = tid & 3, n0 = 2 * p;
    const int c = ch2 * 48 + ca;          // global channel

    __shared__ float uu[48 * 52];         // u[ca][j]
    __shared__ float dd[48 * 52];         // delta[ca][j]
    __shared__ float xr[6 * 52];          // dts rows [r][j]
    __shared__ float bc[48 * 20];         // [j][v]: v<8 B(n), v>=8 C(n)

    // per-lane parameters in registers
    const float* wp = dtw_g + (size_t)qk * CN * RR + c * RR;
    float wdt[6];
    {
        float2 wa = *reinterpret_cast<const float2*>(wp);
        float2 wb = *reinterpret_cast<const float2*>(wp + 2);
        float2 wc = *reinterpret_cast<const float2*>(wp + 4);
        wdt[0] = wa.x; wdt[1] = wa.y; wdt[2] = wb.x; wdt[3] = wb.y; wdt[4] = wc.x; wdt[5] = wc.y;
    }
    const float dtbc = dtb_g[qk * CN + c];
    const float A0 = -__expf(Alog_g[((size_t)qk * CN + c) * NNS + n0]);
    const float A1 = -__expf(Alog_g[((size_t)qk * CN + c) * NNS + n0 + 1]);
    const float Dc = Ds_g[qk * CN + c];
    float h0 = 0.f, h1 = 0.f;

    const bf16* __restrict__ src = (k & 1) ? ztT : zt;
    const bool rev = (k >= 2);
    const int ja = p * 12;

    // u staging pointers: 3 x uint2 (4 bf16 each) per chunk
    const bf16* gu = src + (size_t)(qb * CN + c) * LL + (rev ? (LL - 12 - ja) : ja);
    const int ustep = rev ? -48 : 48;

    // xdbl staging: threads 0..131 stage one uint4 from row vr
    const bool xload = (tid < 132);
    const int vr = tid / 6, jx = (tid % 6) * 8;
    const bf16* gx = xdbl + (size_t)(qb * NK + k) * (DPJ * LL) + (size_t)vr * LL + jx;

    bf16* yp = ys + (size_t)(qb * NK + k) * (CN * LL) + (size_t)c * LL;  // p==0 stores

    uint2 pu0 = *reinterpret_cast<const uint2*>(gu);
    uint2 pu1 = *reinterpret_cast<const uint2*>(gu + 4);
    uint2 pu2 = *reinterpret_cast<const uint2*>(gu + 8);
    uint4 px = {0,0,0,0};
    if (xload) px = *reinterpret_cast<const uint4*>(gx);

    for (int ch = 0; ch < 48; ++ch) {
        __syncthreads();    // prev chunk's LDS reads complete
        // ---- commit u ----
        {
            float e[12];
            unpack4(pu0, e); unpack4(pu1, e + 4); unpack4(pu2, e + 8);
            float f[12];
            #pragma unroll
            for (int i = 0; i < 12; ++i) f[i] = rev ? e[11 - i] : e[i];
            float4* up = reinterpret_cast<float4*>(&uu[ca * 52 + ja]);
            up[0] = make_float4(f[0], f[1], f[2], f[3]);
            up[1] = make_float4(f[4], f[5], f[6], f[7]);
            up[2] = make_float4(f[8], f[9], f[10], f[11]);
        }
        // ---- commit x rows ----
        if (xload) {
            float f[8]; unpack8(px, f);
            if (vr < 6) {
                *reinterpret_cast<float4*>(&xr[vr * 52 + jx])     = make_float4(f[0], f[1], f[2], f[3]);
                *reinterpret_cast<float4*>(&xr[vr * 52 + jx + 4]) = make_float4(f[4], f[5], f[6], f[7]);
            } else {
                int v = vr - 6;
                #pragma unroll
                for (int i = 0; i < 8; ++i) bc[(jx + i) * 20 + v] = f[i];
            }
        }
        __syncthreads();
        // ---- prefetch next chunk ----
        if (ch < 47) {
            gu += ustep;
            pu0 = *reinterpret_cast<const uint2*>(gu);
            pu1 = *reinterpret_cast<const uint2*>(gu + 4);
            pu2 = *reinterpret_cast<const uint2*>(gu + 8);
            if (xload) { gx += 48; px = *reinterpret_cast<const uint4*>(gx); }
        }
        // ---- delta = softplus(wdt . dts + dtb) for j = ja..ja+11 of channel ca ----
        {
            float acc[12];
            #pragma unroll
            for (int i = 0; i < 12; ++i) acc[i] = dtbc;
            #pragma unroll
            for (int r = 0; r < 6; ++r) {
                float4 d0 = *reinterpret_cast<const float4*>(&xr[r * 52 + ja]);
                float4 d1 = *reinterpret_cast<const float4*>(&xr[r * 52 + ja + 4]);
                float4 d2 = *reinterpret_cast<const float4*>(&xr[r * 52 + ja + 8]);
                float w = wdt[r];
                acc[0] = fmaf(w, d0.x, acc[0]); acc[1] = fmaf(w, d0.y, acc[1]);
                acc[2] = fmaf(w, d0.z, acc[2]); acc[3] = fmaf(w, d0.w, acc[3]);
                acc[4] = fmaf(w, d1.x, acc[4]); acc[5] = fmaf(w, d1.y, acc[5]);
                acc[6] = fmaf(w, d1.z, acc[6]); acc[7] = fmaf(w, d1.w, acc[7]);
                acc[8] = fmaf(w, d2.x, acc[8]); acc[9] = fmaf(w, d2.y, acc[9]);
                acc[10] = fmaf(w, d2.z, acc[10]); acc[11] = fmaf(w, d2.w, acc[11]);
            }
            #pragma unroll
            for (int i = 0; i < 12; ++i) {
                float a = acc[i];
                acc[i] = (a > 15.f) ? a : __logf(1.f + __expf(a));
            }
            float4* dp = reinterpret_cast<float4*>(&dd[ca * 52 + ja]);
            dp[0] = make_float4(acc[0], acc[1], acc[2], acc[3]);
            dp[1] = make_float4(acc[4], acc[5], acc[6], acc[7]);
            dp[2] = make_float4(acc[8], acc[9], acc[10], acc[11]);
        }
        __syncthreads();
        // ---- scan 48 steps (j-pairs), pack 8 -> uint4 store by p==0 ----
        const int l0 = ch * 48;
        #pragma unroll
        for (int g = 0; g < 6; ++g) {
            unsigned pk[4];
            #pragma unroll
            for (int jj = 0; jj < 4; ++jj) {
                const int j = g * 8 + jj * 2;
                float2 u2 = *reinterpret_cast<const float2*>(&uu[ca * 52 + j]);
                float2 d2 = *reinterpret_cast<const float2*>(&dd[ca * 52 + j]);
                float2 Ba = *reinterpret_cast<const float2*>(&bc[j * 20 + n0]);
                float2 Ca = *reinterpret_cast<const float2*>(&bc[j * 20 + 8 + n0]);
                float2 Bb = *reinterpret_cast<const float2*>(&bc[(j + 1) * 20 + n0]);
                float2 Cb = *reinterpret_cast<const float2*>(&bc[(j + 1) * 20 + 8 + n0]);
                float ya, yb;
                {
                    float u = u2.x, d = d2.x, du = d * u;
                    float dA0 = __expf(d * A0), dA1 = __expf(d * A1);
                    h0 = fmaf(dA0, h0, du * Ba.x);
                    h1 = fmaf(dA1, h1, du * Ba.y);
                    float y = fmaf(h0, Ca.x, h1 * Ca.y);
                    y += qxor(y, 1); y += qxor(y, 0);
                    ya = fmaf(Dc, u, y);
                }
                {
                    float u = u2.y, d = d2.y, du = d * u;
                    float dA0 = __expf(d * A0), dA1 = __expf(d * A1);
                    h0 = fmaf(dA0, h0, du * Bb.x);
                    h1 = fmaf(dA1, h1, du * Bb.y);
                    float y = fmaf(h0, Cb.x, h1 * Cb.y);
                    y += qxor(y, 1); y += qxor(y, 0);
                    yb = fmaf(Dc, u, y);
                }
                pk[jj] = packbf(ya, yb);
            }
            if (p == 0) {
                uint4 w; w.x = pk[0]; w.y = pk[1]; w.z = pk[2]; w.w = pk[3];
                *reinterpret_cast<uint4*>(yp + l0 + g * 8) = w;
            }
        }
    }
}

// ============================================================================
// K4b: k_sum — combine 4 directions into one tensor at combine-index m:
//   s[c][m] = T(ys0)[m] + ys1[m] + revT(ys2)[m] + rev(ys3)[m]
// All global reads coalesced; transposes via padded LDS tiles.
// grid (96, 16, 4) = (c, b, q), block 256
// ============================================================================
__global__ __launch_bounds__(256) void k_sum(
    const bf16* __restrict__ ys, bf16* __restrict__ s_out)
{
    const int c = blockIdx.x, b = blockIdx.y, q = blockIdx.z;
    const int qb = q * BQ + b;
    const int tid = threadIdx.x;
    __shared__ float t0[48 * 49];
    __shared__ float t2[48 * 49];
    const size_t base0 = ((size_t)(qb * NK + 0) * CN + c) * LL;
    const size_t base1 = ((size_t)(qb * NK + 1) * CN + c) * LL;
    const size_t base2 = ((size_t)(qb * NK + 2) * CN + c) * LL;
    const size_t base3 = ((size_t)(qb * NK + 3) * CN + c) * LL;
    for (int idx = tid; idx < 288; idx += 256) {
        int e0 = idx * 8, h = e0 / 48, w = e0 % 48;
        float f[8];
        unpack8(*reinterpret_cast<const uint4*>(&ys[base0 + e0]), f);
        #pragma unroll
        for (int i = 0; i < 8; ++i) t0[h * 49 + w + i] = f[i];
        unpack8(*reinterpret_cast<const uint4*>(&ys[base2 + e0]), f);
        #pragma unroll
        for (int i = 0; i < 8; ++i) t2[h * 49 + w + i] = f[i];
    }
    __syncthreads();
    const size_t cbase = ((size_t)qb * CN + c) * LL;
    for (int idx = tid; idx < 288; idx += 256) {
        int m0 = idx * 8, ww = m0 / 48, hh = m0 % 48;
        float f1[8], f3[8];
        unpack8(*reinterpret_cast<const uint4*>(&ys[base1 + m0]), f1);
        unpack8(*reinterpret_cast<const uint4*>(&ys[base3 + (LL - 8 - m0)]), f3);
        float o[8];
        #pragma unroll
        for (int i = 0; i < 8; ++i) {
            float v0 = t0[(hh + i) * 49 + ww];
            float v2 = t2[(47 - hh - i) * 49 + (47 - ww)];
            o[i] = v0 + f1[i] + v2 + f3[7 - i];
        }
        uint4 w;
        w.x = packbf(o[0], o[1]); w.y = packbf(o[2], o[3]);
        w.z = packbf(o[4], o[5]); w.w = packbf(o[6], o[7]);
        *reinterpret_cast<uint4*>(&s_out[cbase + m0]) = w;
    }
}

// ============================================================================
// K5: combine: LN(ssln) + LN(p2n) + y=a*z + attention partial sums
// grid (48, 16, 4) = (ww, b, q), block 256 — all global access coalesced
// ============================================================================
__global__ __launch_bounds__(256) void k_combine(
    const bf16* __restrict__ s_in, const bf16* __restrict__ a_in,
    const float* __restrict__ ssg, const float* __restrict__ ssb,
    const float* __restrict__ png, const float* __restrict__ pnb,
    const int* __restrict__ bidx,
    bf16* __restrict__ y_out, float* __restrict__ s_buf)
{
    const int ww = blockIdx.x, b = blockIdx.y, q = blockIdx.z;
    const int qb = q * BQ + b;
    const int tid = threadIdx.x;
    __shared__ float o[CN * 48];
    __shared__ float mu[48], rs[48];
    for (int v = tid; v < 576; v += 256) {
        int e0 = v * 8, cc = e0 / 48, hh = e0 % 48;
        float f[8];
        unpack8(*reinterpret_cast<const uint4*>(&s_in[((size_t)qb * CN + cc) * LL + ww * 48 + hh]), f);
        #pragma unroll
        for (int i = 0; i < 8; ++i) o[cc * 48 + hh + i] = f[i];
    }
    __syncthreads();
    if (tid < 48) {
        float s = 0.f, s2 = 0.f;
        for (int cc = 0; cc < CN; ++cc) { float v = o[cc * 48 + tid]; s += v; s2 += v * v; }
        float m = s * (1.f / 96.f), var = s2 * (1.f / 96.f) - m * m;
        mu[tid] = m; rs[tid] = rsqrtf(var + 1e-6f);
    }
    __syncthreads();
    for (int t = tid; t < CN * 48; t += 256) {
        int cc = t / 48, hh = t % 48;
        o[t] = (o[t] - mu[hh]) * rs[hh] * ssg[q * CN + cc] + ssb[q * CN + cc];
    }
    __syncthreads();
    if (tid < 48) {
        float s = 0.f, s2 = 0.f;
        for (int cc = 0; cc < CN; ++cc) { float v = o[cc * 48 + tid]; s += v; s2 += v * v; }
        float m = s * (1.f / 96.f), var = s2 * (1.f / 96.f) - m * m;
        mu[tid] = m; rs[tid] = rsqrtf(var + 1e-6f);
    }
    __syncthreads();
    const bool even = ((bidx[0] & 1) == 0);
    if (even) {
        for (int v = tid; v < 576; v += 256) {
            int e0 = v * 8, cc = e0 / 48, hh = e0 % 48;
            size_t oidx = ((size_t)qb * CN + cc) * LL + ww * 48 + hh;
            float af[8];
            unpack8(*reinterpret_cast<const uint4*>(&a_in[oidx]), af);
            float yv[8];
            #pragma unroll
            for (int i = 0; i < 8; ++i) {
                float z2 = (o[cc * 48 + hh + i] - mu[hh + i]) * rs[hh + i] * png[q * CN + cc] + pnb[q * CN + cc];
                yv[i] = af[i] * z2;
                o[cc * 48 + hh + i] = yv[i];
            }
            uint4 w;
            w.x = packbf(yv[0], yv[1]); w.y = packbf(yv[2], yv[3]);
            w.z = packbf(yv[4], yv[5]); w.w = packbf(yv[6], yv[7]);
            *reinterpret_cast<uint4*>(&y_out[oidx]) = w;
        }
    } else {
        for (int t = tid; t < CN * 48; t += 256) {
            int cc = t / 48, hh = t % 48;
            float z2 = (o[t] - mu[hh]) * rs[hh] * png[q * CN + cc] + pnb[q * CN + cc];
            size_t oidx = ((size_t)qb * CN + cc) * LL + (47 - hh) * 48 + (47 - ww);
            float yv = b2f(a_in[oidx]) * z2;
            y_out[oidx] = f2b(yv);
            o[t] = yv;
        }
    }
    __syncthreads();
    if (tid < CN) {
        float s = 0.f;
        for (int j = 0; j < 48; ++j) s += o[tid * 48 + j];
        atomicAdd(&s_buf[qb * CN + tid], s);
    }
}

// ============================================================================
// K6: channel attention
// grid (16, 4), block 128
// ============================================================================
__global__ __launch_bounds__(128) void k_attn(
    const float* __restrict__ s_buf,
    const float* __restrict__ w1, const float* __restrict__ b1,
    const float* __restrict__ w2, const float* __restrict__ b2,
    float* __restrict__ att)
{
    const int b = blockIdx.x, q = blockIdx.y;
    const int qb = q * BQ + b;
    const int tid = threadIdx.x;
    __shared__ float sm[CN], tl[CRr];
    if (tid < CN) sm[tid] = s_buf[qb * CN + tid] * (1.f / (float)LL);
    __syncthreads();
    if (tid < CRr) {
        float acc = b1[q * CRr + tid];
        for (int cc = 0; cc < CN; ++cc)
            acc = fmaf(w1[(q * CRr + tid) * CN + cc], sm[cc], acc);
        tl[tid] = siluf(acc);
    }
    __syncthreads();
    if (tid < CN) {
        float acc = b2[q * CN + tid];
        #pragma unroll
        for (int r = 0; r < CRr; ++r)
            acc = fmaf(w2[(q * CN + tid) * CRr + r], tl[r], acc);
        att[qb * CN + tid] = sigf(acc);
    }
}

// ============================================================================
// K7: out = x + y * att  (vectorized)
// grid (96, 16, 4) = (c, b, q), block 256
// ============================================================================
__global__ __launch_bounds__(256) void k_final(
    const float* __restrict__ x, const bf16* __restrict__ y_in,
    const float* __restrict__ att, float* __restrict__ out)
{
    const int c = blockIdx.x, b = blockIdx.y, q = blockIdx.z;
    const int h0 = (q >> 1) * HQ, w0 = (q & 1) * HQ;
    const int qb = q * BQ + b;
    const float av = att[qb * CN + c];
    const size_t ybase = (size_t)(qb * CN + c) * LL;
    const int xb = (b * CN + c) * 9216 + h0 * 96 + w0;
    for (int t = threadIdx.x; t < LL / 8; t += 256) {
        int e0 = t * 8;
        int gi = xb + (e0 / 48) * 96 + (e0 % 48);
        uint4 yv = *reinterpret_cast<const uint4*>(&y_in[ybase + e0]);
        float yf[8]; unpack8(yv, yf);
        float4 xa = *reinterpret_cast<const float4*>(&x[gi]);
        float4 xc = *reinterpret_cast<const float4*>(&x[gi + 4]);
        float4 o0 = {xa.x + yf[0]*av, xa.y + yf[1]*av, xa.z + yf[2]*av, xa.w + yf[3]*av};
        float4 o1 = {xc.x + yf[4]*av, xc.y + yf[5]*av, xc.z + yf[6]*av, xc.w + yf[7]*av};
        *reinterpret_cast<float4*>(&out[gi])     = o0;
        *reinterpret_cast<float4*>(&out[gi + 4]) = o1;
    }
}

// ============================================================================
extern "C" void kernel_launch(void* const* d_in, const int* in_sizes, int n_in,
                              void* d_out, int out_size, void* d_ws, size_t ws_size,
                              hipStream_t stream)
{
    (void)in_sizes; (void)n_in; (void)out_size; (void)ws_size;
    const float* x       = (const float*)d_in[0];
    const float* ln_g    = (const float*)d_in[1];
    const float* ln_b    = (const float*)d_in[2];
    const float* p1_w    = (const float*)d_in[3];
    const float* p1_b    = (const float*)d_in[4];
    const float* p2in_w  = (const float*)d_in[5];
    const float* p2in_b  = (const float*)d_in[6];
    const float* dw_w    = (const float*)d_in[7];
    const float* dw_b    = (const float*)d_in[8];
    const float* xproj_w = (const float*)d_in[9];
    const float* dtproj_w= (const float*)d_in[10];
    const float* dtproj_b= (const float*)d_in[11];
    const float* A_logs  = (const float*)d_in[12];
    const float* Ds      = (const float*)d_in[13];
    const float* ssln_g  = (const float*)d_in[14];
    const float* ssln_b  = (const float*)d_in[15];
    const float* p2n_g   = (const float*)d_in[16];
    const float* p2n_b   = (const float*)d_in[17];
    const float* ca_w1   = (const float*)d_in[18];
    const float* ca_b1   = (const float*)d_in[19];
    const float* ca_w2   = (const float*)d_in[20];
    const float* ca_b2   = (const float*)d_in[21];
    const int*  bidx     = (const int*)d_in[22];
    float* out = (float*)d_out;

    char* ws = (char*)d_ws;
    const size_t off_a    = 0;                                  // bf16, live K1->K5
    const size_t off_zt   = 28311552;                           // bf16, live K2->K4
    const size_t off_ztT  = 56623104;                           // bf16, live K2->K4
    const size_t off_xdbl = 84934656;                           // bf16, live K3->K4
    const size_t off_ys   = 110886912;                          // bf16, live K4->K4b
    const size_t off_z0   = off_ys;                             // fp32 alias (dead before ys)
    const size_t off_s    = off_zt;                             // bf16 alias: sum tensor (K4b->K5)
    const size_t off_y    = off_ztT;                            // bf16 alias: gated y (K5->K7)
    const size_t off_sb   = 224133120;                          // fp32 attention sums
    const size_t off_att  = off_sb + 24576;                     // fp32

    bf16*  a_buf   = (bf16*)(ws + off_a);
    bf16*  zt_buf  = (bf16*)(ws + off_zt);
    bf16*  ztT_buf = (bf16*)(ws + off_ztT);
    bf16*  xdbl_buf= (bf16*)(ws + off_xdbl);
    bf16*  ys_buf  = (bf16*)(ws + off_ys);
    float* z0_buf  = (float*)(ws + off_z0);
    bf16*  s_sum   = (bf16*)(ws + off_s);
    bf16*  y_buf   = (bf16*)(ws + off_y);
    float* s_buf   = (float*)(ws + off_sb);
    float* att_buf = (float*)(ws + off_att);

    (void)hipMemsetAsync(ws + off_sb, 0, 24576, stream);

    k_lnconv<<<dim3(24, 16, 4), 192, 0, stream>>>(
        x, ln_g, ln_b, p1_w, p1_b, p2in_w, p2in_b, a_buf, z0_buf);
    k_dwconv<<<dim3(96, 16, 4), 256, 0, stream>>>(
        z0_buf, dw_w, dw_b, bidx, zt_buf, ztT_buf);
    k_xdbl<<<dim3(12, 4, 64), 256, 0, stream>>>(
        zt_buf, ztT_buf, xproj_w, xdbl_buf);
    k_scan<<<dim3(512), 192, 0, stream>>>(
        zt_buf, ztT_buf, xdbl_buf, dtproj_w, dtproj_b, A_logs, Ds, ys_buf);
    k_sum<<<dim3(96, 16, 4), 256, 0, stream>>>(
        ys_buf, s_sum);
    k_combine<<<dim3(48, 16, 4), 256, 0, stream>>>(
        s_sum, a_buf, ssln_g, ssln_b, p2n_g, p2n_b, bidx, y_buf, s_buf);
    k_attn<<<dim3(16, 4), 128, 0, stream>>>(
        s_buf, ca_w1, ca_b1, ca_w2, ca_b2, att_buf);
    k_final<<<dim3(96, 16, 4), 256, 0, stream>>>(
        x, y_buf, att_buf, out);
}

// Round 6
// 733.851 us; speedup vs baseline: 1.8421x; 1.0513x over previous
//
#include <hip/hip_runtime.h>
#include <hip/hip_bf16.h>

// ---- problem constants ----
#define BQ 16      // batch
#define CN 96      // channels
#define HQ 48      // quadrant H = W
#define LL 2304    // HQ*HQ
#define NK 4       // scan directions
#define RR 6       // dt rank
#define NNS 8      // state size
#define DPJ 22     // R + 2N
#define CRr 12     // attention rank
#define LOG2E 1.4426950408889634f

using bf16 = __hip_bfloat16;

__device__ __forceinline__ float b2f(bf16 v) { return __bfloat162float(v); }
__device__ __forceinline__ bf16  f2b(float v){ return __float2bfloat16(v); }
__device__ __forceinline__ float bflo(unsigned u){ return __uint_as_float(u << 16); }
__device__ __forceinline__ float bfhi(unsigned u){ return __uint_as_float(u & 0xffff0000u); }
__device__ __forceinline__ float sigf(float x){ return 1.f / (1.f + __expf(-x)); }
__device__ __forceinline__ float siluf(float x){ return x / (1.f + __expf(-x)); }
__device__ __forceinline__ unsigned packbf(float a, float b){
    unsigned lo = (unsigned)__builtin_bit_cast(unsigned short, f2b(a));
    unsigned hi = (unsigned)__builtin_bit_cast(unsigned short, f2b(b));
    return lo | (hi << 16);
}
__device__ __forceinline__ unsigned rot16(unsigned u){ return (u >> 16) | (u << 16); }
__device__ __forceinline__ void unpack8(uint4 v, float* f){
    f[0]=bflo(v.x); f[1]=bfhi(v.x); f[2]=bflo(v.y); f[3]=bfhi(v.y);
    f[4]=bflo(v.z); f[5]=bfhi(v.z); f[6]=bflo(v.w); f[7]=bfhi(v.w);
}
__device__ __forceinline__ void unpack4(uint2 v, float* f){
    f[0]=bflo(v.x); f[1]=bfhi(v.x); f[2]=bflo(v.y); f[3]=bfhi(v.y);
}
__device__ __forceinline__ float fexp2(float x){
#if __has_builtin(__builtin_amdgcn_exp2f)
    return __builtin_amdgcn_exp2f(x);
#else
    return __expf(x * 0.6931471805599453f);
#endif
}
// quad_perm DPP xor within groups of 4 lanes (VALU pipe, no LDS)
__device__ __forceinline__ float qxor(float v, int ctrl_b1){
    int x;
    if (ctrl_b1) x = __builtin_amdgcn_mov_dpp(__float_as_int(v), 0xB1, 0xF, 0xF, true);
    else         x = __builtin_amdgcn_mov_dpp(__float_as_int(v), 0x4E, 0xF, 0xF, true);
    return __int_as_float(x);
}

// ============================================================================
// K1: channel LN + conv1x1 (a-branch with silu, z-branch raw -> bf16)
// grid (24, 16, 4) = (hh-pair, b, q), block 192
// ============================================================================
__global__ __launch_bounds__(192) void k_lnconv(
    const float* __restrict__ x, const float* __restrict__ ln_g, const float* __restrict__ ln_b,
    const float* __restrict__ p1w, const float* __restrict__ p1b,
    const float* __restrict__ p2w, const float* __restrict__ p2b,
    bf16* __restrict__ a_out, bf16* __restrict__ z0_out)
{
    const int hh2 = blockIdx.x;           // 0..23 (covers 2 rows each)
    const int b = blockIdx.y, q = blockIdx.z;
    const int h0 = (q >> 1) * HQ, w0 = (q & 1) * HQ;
    const int tid = threadIdx.x;
    const int qb = q * BQ + b;

    __shared__ alignas(16) bf16 hn[CN * 96];    // [c][p], p = local pos 0..95 (2 rows x 48)
    __shared__ alignas(16) bf16 wl[CN * 200];   // [c][row 0..191, pad to 200]
    __shared__ float mu[96], rs[96];

    // stage weights transposed: wl[c][d] = p1, wl[c][96+d] = p2in
    for (int t = tid; t < CN * CN; t += 192) {
        int d = t / CN, c = t % CN;
        wl[c * 200 + d]      = f2b(p1w[(q * CN + d) * CN + c]);
        wl[c * 200 + 96 + d] = f2b(p2w[(q * CN + d) * CN + c]);
    }
    // stage x tile: float4 loads, packed uint2 LDS writes
    for (int t = tid; t < CN * 24; t += 192) {
        int c = t / 24, v = t % 24;
        int row = v / 12, col = (v % 12) * 4;
        float4 xv = *reinterpret_cast<const float4*>(
            &x[((b * CN + c) * 96 + h0 + 2 * hh2 + row) * 96 + w0 + col]);
        uint2 pk; pk.x = packbf(xv.x, xv.y); pk.y = packbf(xv.z, xv.w);
        *reinterpret_cast<uint2*>(&hn[c * 96 + v * 4]) = pk;
    }
    __syncthreads();
    // LN stats per position
    if (tid < 96) {
        float s = 0.f, s2 = 0.f;
        for (int c = 0; c < CN; ++c) { float v = b2f(hn[c * 96 + tid]); s += v; s2 += v * v; }
        float m = s * (1.f / 96.f);
        float var = s2 * (1.f / 96.f) - m * m;
        mu[tid] = m; rs[tid] = rsqrtf(var + 1e-6f);
    }
    __syncthreads();
    // normalize in place
    for (int t = tid; t < CN * 96; t += 192) {
        int c = t / 96, p = t % 96;
        float g = ln_g[q * CN + c], bb = ln_b[q * CN + c];
        hn[t] = f2b((b2f(hn[t]) - mu[p]) * rs[p] * g + bb);
    }
    __syncthreads();
    // matvec: thread -> 8 output rows x 12 positions
    const int rg = tid >> 3, pg = tid & 7;
    const int row0 = rg * 8, pp0 = pg * 12;
    float acc[8][12];
    #pragma unroll
    for (int i = 0; i < 8; ++i)
        #pragma unroll
        for (int j = 0; j < 12; ++j) acc[i][j] = 0.f;

    for (int c = 0; c < CN; ++c) {
        uint4 wv = *reinterpret_cast<const uint4*>(&wl[c * 200 + row0]);
        float w[8];
        w[0] = bflo(wv.x); w[1] = bfhi(wv.x);
        w[2] = bflo(wv.y); w[3] = bfhi(wv.y);
        w[4] = bflo(wv.z); w[5] = bfhi(wv.z);
        w[6] = bflo(wv.w); w[7] = bfhi(wv.w);
        uint2 ha = *reinterpret_cast<const uint2*>(&hn[c * 96 + pp0]);
        uint2 hb = *reinterpret_cast<const uint2*>(&hn[c * 96 + pp0 + 4]);
        uint2 hc = *reinterpret_cast<const uint2*>(&hn[c * 96 + pp0 + 8]);
        float hv[12];
        hv[0] = bflo(ha.x); hv[1] = bfhi(ha.x); hv[2]  = bflo(ha.y); hv[3]  = bfhi(ha.y);
        hv[4] = bflo(hb.x); hv[5] = bfhi(hb.x); hv[6]  = bflo(hb.y); hv[7]  = bfhi(hb.y);
        hv[8] = bflo(hc.x); hv[9] = bfhi(hc.x); hv[10] = bflo(hc.y); hv[11] = bfhi(hc.y);
        #pragma unroll
        for (int i = 0; i < 8; ++i)
            #pragma unroll
            for (int j = 0; j < 12; ++j)
                acc[i][j] = fmaf(w[i], hv[j], acc[i][j]);
    }
    // epilogue: packed bf16 stores (12 contiguous elems per row)
    const int lbase = (2 * hh2 + pp0 / 48) * 48 + (pp0 % 48);
    #pragma unroll
    for (int i = 0; i < 8; ++i) {
        int row = row0 + i;
        bool isA = row < 96;
        int d = isA ? row : row - 96;
        float bias = isA ? p1b[q * CN + d] : p2b[q * CN + d];
        int oidx = (qb * CN + d) * LL + lbase;
        float v[12];
        #pragma unroll
        for (int j = 0; j < 12; ++j) v[j] = acc[i][j] + bias;
        if (isA) {
            #pragma unroll
            for (int j = 0; j < 12; ++j) v[j] = siluf(v[j]);
        }
        uint2 w0p, w1p, w2p;
        w0p.x = packbf(v[0], v[1]);  w0p.y = packbf(v[2], v[3]);
        w1p.x = packbf(v[4], v[5]);  w1p.y = packbf(v[6], v[7]);
        w2p.x = packbf(v[8], v[9]);  w2p.y = packbf(v[10], v[11]);
        bf16* dst = isA ? a_out : z0_out;
        *reinterpret_cast<uint2*>(&dst[oidx])     = w0p;
        *reinterpret_cast<uint2*>(&dst[oidx + 4]) = w1p;
        *reinterpret_cast<uint2*>(&dst[oidx + 8]) = w2p;
    }
}

// ============================================================================
// K2: depthwise 3x3 SAME + bias + silu + block_idx transform (bf16 in/out)
// grid (96, 16, 4) = (c, b, q), block 256
// ============================================================================
__global__ __launch_bounds__(256) void k_dwconv(
    const bf16* __restrict__ z0, const float* __restrict__ dww, const float* __restrict__ dwb,
    const int* __restrict__ bidx, bf16* __restrict__ zt, bf16* __restrict__ ztT)
{
    const int c = blockIdx.x, b = blockIdx.y, q = blockIdx.z;
    const int tid = threadIdx.x;
    const int base = ((q * BQ + b) * CN + c) * LL;
    __shared__ float zin[LL];
    __shared__ float zo[48 * 49];   // padded rows: conflict-free transposed reads
    for (int t = tid; t < 288; t += 256) {
        uint4 v = *reinterpret_cast<const uint4*>(&z0[base + t * 8]);
        float f[8]; unpack8(v, f);
        *reinterpret_cast<float4*>(&zin[t * 8])     = make_float4(f[0], f[1], f[2], f[3]);
        *reinterpret_cast<float4*>(&zin[t * 8 + 4]) = make_float4(f[4], f[5], f[6], f[7]);
    }
    float wk[9];
    #pragma unroll
    for (int i = 0; i < 9; ++i) wk[i] = dww[(q * CN + c) * 9 + i];
    const float bias = dwb[q * CN + c];
    __syncthreads();
    for (int t = tid; t < LL; t += 256) {
        int hh = t / 48, ww = t % 48;
        float s = bias;
        #pragma unroll
        for (int dy = -1; dy <= 1; ++dy)
            #pragma unroll
            for (int dx = -1; dx <= 1; ++dx) {
                int yy = hh + dy, xx = ww + dx;
                if (yy >= 0 && yy < 48 && xx >= 0 && xx < 48)
                    s = fmaf(wk[(dy + 1) * 3 + (dx + 1)], zin[yy * 48 + xx], s);
            }
        zo[hh * 49 + ww] = siluf(s);
    }
    __syncthreads();
    const bool even = ((bidx[0] & 1) == 0);
    for (int t = tid; t < LL; t += 256) {
        int i = t / 48, j = t % 48;
        float vz, vzT;
        if (even) { vz = zo[j * 49 + i];               vzT = zo[i * 49 + j]; }
        else      { vz = zo[(47 - i) * 49 + (47 - j)]; vzT = zo[(47 - j) * 49 + (47 - i)]; }
        zt[base + t]  = f2b(vz);
        ztT[base + t] = f2b(vzT);
    }
}

// ============================================================================
// K3: x_dbl = xproj_w @ u_k  (direction mapping + reversal folded in)
// grid (12, 4, 64) = (l-tile, k, q*16+b), block 256
// compute retiled: 2 d-rows x 12 l = 176 tiles, single pass
// ============================================================================
__global__ __launch_bounds__(256) void k_xdbl(
    const bf16* __restrict__ zt, const bf16* __restrict__ ztT,
    const float* __restrict__ xprojw, bf16* __restrict__ xdbl)
{
    const int lt = blockIdx.x, k = blockIdx.y, qb = blockIdx.z;
    const int tid = threadIdx.x;
    const int l0 = lt * 192;
    const int q = qb >> 4;
    __shared__ alignas(16) bf16 ul[CN * 200];
    __shared__ alignas(16) bf16 wl[CN * 24];    // transposed [c][d], pad 22->24
    const bf16* __restrict__ src = (k & 1) ? ztT : zt;
    const bool rev = (k >= 2);
    // vectorized staging: 96c x 24 vectors of 8 bf16
    for (int t = tid; t < CN * 24; t += 256) {
        int cc = t / 24, j0 = (t % 24) * 8;
        uint4 v;
        if (!rev) {
            v = *reinterpret_cast<const uint4*>(&src[(size_t)(qb * CN + cc) * LL + l0 + j0]);
        } else {
            v = *reinterpret_cast<const uint4*>(&src[(size_t)(qb * CN + cc) * LL + (LL - (l0 + j0) - 8)]);
            uint4 r; r.x = rot16(v.w); r.y = rot16(v.z); r.z = rot16(v.y); r.w = rot16(v.x);
            v = r;
        }
        *reinterpret_cast<uint4*>(&ul[cc * 200 + j0]) = v;
    }
    for (int t = tid; t < DPJ * CN; t += 256) {
        int d = t / CN, c = t % CN;
        wl[c * 24 + d] = f2b(xprojw[(q * NK + k) * DPJ * CN + t]);
    }
    __syncthreads();
    // tiles: 2 d-rows x 12 l : 11 * 16 = 176 tiles, single pass
    if (tid < 176) {
        const int dp = tid / 16, lg = tid % 16;
        const int d0 = dp * 2, llp = lg * 12;
        float acc0[12], acc1[12];
        #pragma unroll
        for (int j = 0; j < 12; ++j) { acc0[j] = 0.f; acc1[j] = 0.f; }
        for (int c = 0; c < CN; ++c) {
            unsigned wv = *reinterpret_cast<const unsigned*>(&wl[c * 24 + d0]);
            float w0 = bflo(wv), w1 = bfhi(wv);
            uint2 ua = *reinterpret_cast<const uint2*>(&ul[c * 200 + llp]);
            uint2 ub = *reinterpret_cast<const uint2*>(&ul[c * 200 + llp + 4]);
            uint2 uc = *reinterpret_cast<const uint2*>(&ul[c * 200 + llp + 8]);
            float uf[12];
            unpack4(ua, uf); unpack4(ub, uf + 4); unpack4(uc, uf + 8);
            #pragma unroll
            for (int j = 0; j < 12; ++j) {
                acc0[j] = fmaf(w0, uf[j], acc0[j]);
                acc1[j] = fmaf(w1, uf[j], acc1[j]);
            }
        }
        int ob = (qb * NK + k) * DPJ * LL + l0 + llp;
        uint2 o0a, o0b, o0c, o1a, o1b, o1c;
        o0a.x = packbf(acc0[0], acc0[1]);  o0a.y = packbf(acc0[2], acc0[3]);
        o0b.x = packbf(acc0[4], acc0[5]);  o0b.y = packbf(acc0[6], acc0[7]);
        o0c.x = packbf(acc0[8], acc0[9]);  o0c.y = packbf(acc0[10], acc0[11]);
        o1a.x = packbf(acc1[0], acc1[1]);  o1a.y = packbf(acc1[2], acc1[3]);
        o1b.x = packbf(acc1[4], acc1[5]);  o1b.y = packbf(acc1[6], acc1[7]);
        o1c.x = packbf(acc1[8], acc1[9]);  o1c.y = packbf(acc1[10], acc1[11]);
        *reinterpret_cast<uint2*>(&xdbl[ob + d0 * LL])           = o0a;
        *reinterpret_cast<uint2*>(&xdbl[ob + d0 * LL + 4])       = o0b;
        *reinterpret_cast<uint2*>(&xdbl[ob + d0 * LL + 8])       = o0c;
        *reinterpret_cast<uint2*>(&xdbl[ob + (d0 + 1) * LL])     = o1a;
        *reinterpret_cast<uint2*>(&xdbl[ob + (d0 + 1) * LL + 4]) = o1b;
        *reinterpret_cast<uint2*>(&xdbl[ob + (d0 + 1) * LL + 8]) = o1c;
    }
}

// ============================================================================
// K4: fused delta(softplus) + selective scan + Ds*u term
// grid (512) = (qb,k,chalf), block 192 = 48 c x 4 lanes (2 states each)
// Software-pipelined double-buffer: 2 barriers/chunk, delta(i+1) || scan(i).
// bcv float4 layout {B0,B1,C0,C1} per (j,p): 1 b128 broadcast read/step.
// exp2 with ln2 folded into A.
// ============================================================================
__global__ __launch_bounds__(192) void k_scan(
    const bf16* __restrict__ zt, const bf16* __restrict__ ztT,
    const bf16* __restrict__ xdbl,
    const float* __restrict__ dtw_g, const float* __restrict__ dtb_g,
    const float* __restrict__ Alog_g, const float* __restrict__ Ds_g,
    bf16* __restrict__ ys)
{
    const int bid = blockIdx.x;
    const int ch2 = bid & 1, k = (bid >> 1) & 3, qb = bid >> 3, q = qb >> 4;
    const int qk = q * NK + k;
    const int tid = threadIdx.x;
    const int ca = tid >> 2, p = tid & 3;
    const int c = ch2 * 48 + ca;          // global channel

    __shared__ float uu[2][48 * 52];
    __shared__ float dd[2][48 * 52];
    __shared__ float xr[2][6 * 52];           // dts rows
    __shared__ float bcv[2][48 * 16];         // [j][p*4 + {B0,B1,C0,C1}]

    // per-lane parameters in registers
    const float* wp = dtw_g + (size_t)qk * CN * RR + c * RR;
    float wdt[6];
    {
        float2 wa = *reinterpret_cast<const float2*>(wp);
        float2 wb = *reinterpret_cast<const float2*>(wp + 2);
        float2 wc = *reinterpret_cast<const float2*>(wp + 4);
        wdt[0] = wa.x; wdt[1] = wa.y; wdt[2] = wb.x; wdt[3] = wb.y; wdt[4] = wc.x; wdt[5] = wc.y;
    }
    const float dtbc = dtb_g[qk * CN + c];
    const float A0L = -__expf(Alog_g[((size_t)qk * CN + c) * NNS + 2 * p])     * LOG2E;
    const float A1L = -__expf(Alog_g[((size_t)qk * CN + c) * NNS + 2 * p + 1]) * LOG2E;
    const float Dc = Ds_g[qk * CN + c];
    float h0 = 0.f, h1 = 0.f;

    const bf16* __restrict__ src = (k & 1) ? ztT : zt;
    const bool rev = (k >= 2);
    const int ja = p * 12;

    // u staging: 3 x uint2 (12 bf16) per chunk per thread
    const bf16* gu = src + (size_t)(qb * CN + c) * LL + (rev ? (LL - 12 - ja) : ja);
    const int ustep = rev ? -48 : 48;

    // xdbl staging: threads 0..131 stage one uint4 (8 bf16) from row vr
    const bool xload = (tid < 132);
    const int vr = tid / 6, jx = (tid % 6) * 8;
    const bf16* gx = xdbl + (size_t)(qb * NK + k) * (DPJ * LL) + (size_t)vr * LL + jx;
    // bcv column for B/C rows
    int bccol = 0;
    if (vr >= 6) {
        int v = vr - 6;           // 0..15: 0-7 B, 8-15 C
        int n = v & 7;
        bccol = (n >> 1) * 4 + ((v >= 8) ? 2 : 0) + (n & 1);
    }

    bf16* yp = ys + (size_t)(qb * NK + k) * (CN * LL) + (size_t)c * LL;  // p==0 stores

    uint2 pu0 = *reinterpret_cast<const uint2*>(gu);
    uint2 pu1 = *reinterpret_cast<const uint2*>(gu + 4);
    uint2 pu2 = *reinterpret_cast<const uint2*>(gu + 8);
    uint4 px = {0,0,0,0};
    if (xload) px = *reinterpret_cast<const uint4*>(gx);

    // ---- commit helper is inlined manually (buffer index passed) ----
    // preamble: commit chunk0 -> buf0
    {
        float e[12];
        unpack4(pu0, e); unpack4(pu1, e + 4); unpack4(pu2, e + 8);
        float f[12];
        #pragma unroll
        for (int i = 0; i < 12; ++i) f[i] = rev ? e[11 - i] : e[i];
        float4* up = reinterpret_cast<float4*>(&uu[0][ca * 52 + ja]);
        up[0] = make_float4(f[0], f[1], f[2], f[3]);
        up[1] = make_float4(f[4], f[5], f[6], f[7]);
        up[2] = make_float4(f[8], f[9], f[10], f[11]);
        if (xload) {
            float g[8]; unpack8(px, g);
            if (vr < 6) {
                *reinterpret_cast<float4*>(&xr[0][vr * 52 + jx])     = make_float4(g[0], g[1], g[2], g[3]);
                *reinterpret_cast<float4*>(&xr[0][vr * 52 + jx + 4]) = make_float4(g[4], g[5], g[6], g[7]);
            } else {
                #pragma unroll
                for (int i = 0; i < 8; ++i) bcv[0][(jx + i) * 16 + bccol] = g[i];
            }
        }
    }
    // prefetch chunk1
    gu += ustep;
    pu0 = *reinterpret_cast<const uint2*>(gu);
    pu1 = *reinterpret_cast<const uint2*>(gu + 4);
    pu2 = *reinterpret_cast<const uint2*>(gu + 8);
    if (xload) { gx += 48; px = *reinterpret_cast<const uint4*>(gx); }
    __syncthreads();
    // delta0 -> dd[0]
    {
        float acc[12];
        #pragma unroll
        for (int i = 0; i < 12; ++i) acc[i] = dtbc;
        #pragma unroll
        for (int r = 0; r < 6; ++r) {
            float4 d0 = *reinterpret_cast<const float4*>(&xr[0][r * 52 + ja]);
            float4 d1 = *reinterpret_cast<const float4*>(&xr[0][r * 52 + ja + 4]);
            float4 d2 = *reinterpret_cast<const float4*>(&xr[0][r * 52 + ja + 8]);
            float w = wdt[r];
            acc[0] = fmaf(w, d0.x, acc[0]);  acc[1] = fmaf(w, d0.y, acc[1]);
            acc[2] = fmaf(w, d0.z, acc[2]);  acc[3] = fmaf(w, d0.w, acc[3]);
            acc[4] = fmaf(w, d1.x, acc[4]);  acc[5] = fmaf(w, d1.y, acc[5]);
            acc[6] = fmaf(w, d1.z, acc[6]);  acc[7] = fmaf(w, d1.w, acc[7]);
            acc[8] = fmaf(w, d2.x, acc[8]);  acc[9] = fmaf(w, d2.y, acc[9]);
            acc[10] = fmaf(w, d2.z, acc[10]); acc[11] = fmaf(w, d2.w, acc[11]);
        }
        #pragma unroll
        for (int i = 0; i < 12; ++i) {
            float a = acc[i];
            acc[i] = (a > 15.f) ? a : __logf(1.f + __expf(a));
        }
        float4* dp = reinterpret_cast<float4*>(&dd[0][ca * 52 + ja]);
        dp[0] = make_float4(acc[0], acc[1], acc[2], acc[3]);
        dp[1] = make_float4(acc[4], acc[5], acc[6], acc[7]);
        dp[2] = make_float4(acc[8], acc[9], acc[10], acc[11]);
    }
    __syncthreads();

    for (int ch = 0; ch < 48; ++ch) {
        const int cur = ch & 1, nxt = cur ^ 1;
        // ---- commit chunk ch+1 into buf[nxt] ----
        if (ch < 47) {
            float e[12];
            unpack4(pu0, e); unpack4(pu1, e + 4); unpack4(pu2, e + 8);
            float f[12];
            #pragma unroll
            for (int i = 0; i < 12; ++i) f[i] = rev ? e[11 - i] : e[i];
            float4* up = reinterpret_cast<float4*>(&uu[nxt][ca * 52 + ja]);
            up[0] = make_float4(f[0], f[1], f[2], f[3]);
            up[1] = make_float4(f[4], f[5], f[6], f[7]);
            up[2] = make_float4(f[8], f[9], f[10], f[11]);
            if (xload) {
                float g[8]; unpack8(px, g);
                if (vr < 6) {
                    *reinterpret_cast<float4*>(&xr[nxt][vr * 52 + jx])     = make_float4(g[0], g[1], g[2], g[3]);
                    *reinterpret_cast<float4*>(&xr[nxt][vr * 52 + jx + 4]) = make_float4(g[4], g[5], g[6], g[7]);
                } else {
                    #pragma unroll
                    for (int i = 0; i < 8; ++i) bcv[nxt][(jx + i) * 16 + bccol] = g[i];
                }
            }
        }
        __syncthreads();
        // ---- prefetch chunk ch+2 ----
        if (ch < 46) {
            gu += ustep;
            pu0 = *reinterpret_cast<const uint2*>(gu);
            pu1 = *reinterpret_cast<const uint2*>(gu + 4);
            pu2 = *reinterpret_cast<const uint2*>(gu + 8);
            if (xload) { gx += 48; px = *reinterpret_cast<const uint4*>(gx); }
        }
        // ---- delta for chunk ch+1 (buf nxt) ----
        if (ch < 47) {
            float acc[12];
            #pragma unroll
            for (int i = 0; i < 12; ++i) acc[i] = dtbc;
            #pragma unroll
            for (int r = 0; r < 6; ++r) {
                float4 d0 = *reinterpret_cast<const float4*>(&xr[nxt][r * 52 + ja]);
                float4 d1 = *reinterpret_cast<const float4*>(&xr[nxt][r * 52 + ja + 4]);
                float4 d2 = *reinterpret_cast<const float4*>(&xr[nxt][r * 52 + ja + 8]);
                float w = wdt[r];
                acc[0] = fmaf(w, d0.x, acc[0]);  acc[1] = fmaf(w, d0.y, acc[1]);
                acc[2] = fmaf(w, d0.z, acc[2]);  acc[3] = fmaf(w, d0.w, acc[3]);
                acc[4] = fmaf(w, d1.x, acc[4]);  acc[5] = fmaf(w, d1.y, acc[5]);
                acc[6] = fmaf(w, d1.z, acc[6]);  acc[7] = fmaf(w, d1.w, acc[7]);
                acc[8] = fmaf(w, d2.x, acc[8]);  acc[9] = fmaf(w, d2.y, acc[9]);
                acc[10] = fmaf(w, d2.z, acc[10]); acc[11] = fmaf(w, d2.w, acc[11]);
            }
            #pragma unroll
            for (int i = 0; i < 12; ++i) {
                float a = acc[i];
                acc[i] = (a > 15.f) ? a : __logf(1.f + __expf(a));
            }
            float4* dp = reinterpret_cast<float4*>(&dd[nxt][ca * 52 + ja]);
            dp[0] = make_float4(acc[0], acc[1], acc[2], acc[3]);
            dp[1] = make_float4(acc[4], acc[5], acc[6], acc[7]);
            dp[2] = make_float4(acc[8], acc[9], acc[10], acc[11]);
        }
        // ---- scan chunk ch (buf cur): 48 steps ----
        {
            const int l0 = ch * 48;
            const float* uuc = &uu[cur][ca * 52];
            const float* ddc = &dd[cur][ca * 52];
            const float* bcc = &bcv[cur][p * 4];
            #pragma unroll
            for (int gg = 0; gg < 6; ++gg) {
                unsigned pk[4];
                #pragma unroll
                for (int half = 0; half < 2; ++half) {
                    const int j0 = gg * 8 + half * 4;
                    float4 u4 = *reinterpret_cast<const float4*>(uuc + j0);
                    float4 d4 = *reinterpret_cast<const float4*>(ddc + j0);
                    const float* uf = reinterpret_cast<const float*>(&u4);
                    const float* df = reinterpret_cast<const float*>(&d4);
                    #pragma unroll
                    for (int s = 0; s < 4; ++s) {
                        float u = uf[s], d = df[s];
                        float4 bq = *reinterpret_cast<const float4*>(bcc + (j0 + s) * 16);
                        float du = d * u;
                        float dA0 = fexp2(d * A0L);
                        float dA1 = fexp2(d * A1L);
                        h0 = fmaf(dA0, h0, du * bq.x);
                        h1 = fmaf(dA1, h1, du * bq.y);
                        float y = fmaf(h0, bq.z, h1 * bq.w);
                        y += qxor(y, 1); y += qxor(y, 0);
                        y = fmaf(Dc, u, y);
                        unsigned hb = (unsigned)__builtin_bit_cast(unsigned short, f2b(y));
                        const int sl = half * 4 + s;
                        if (sl & 1) pk[sl >> 1] |= hb << 16; else pk[sl >> 1] = hb;
                    }
                }
                if (p == 0) {
                    uint4 w; w.x = pk[0]; w.y = pk[1]; w.z = pk[2]; w.w = pk[3];
                    *reinterpret_cast<uint4*>(yp + l0 + gg * 8) = w;
                }
            }
        }
        __syncthreads();
    }
}

// ============================================================================
// K4b: k_sum — combine 4 directions into one tensor at combine-index m
// grid (96, 16, 4) = (c, b, q), block 256
// ============================================================================
__global__ __launch_bounds__(256) void k_sum(
    const bf16* __restrict__ ys, bf16* __restrict__ s_out)
{
    const int c = blockIdx.x, b = blockIdx.y, q = blockIdx.z;
    const int qb = q * BQ + b;
    const int tid = threadIdx.x;
    __shared__ float t0[48 * 49];
    __shared__ float t2[48 * 49];
    const size_t base0 = ((size_t)(qb * NK + 0) * CN + c) * LL;
    const size_t base1 = ((size_t)(qb * NK + 1) * CN + c) * LL;
    const size_t base2 = ((size_t)(qb * NK + 2) * CN + c) * LL;
    const size_t base3 = ((size_t)(qb * NK + 3) * CN + c) * LL;
    for (int idx = tid; idx < 288; idx += 256) {
        int e0 = idx * 8, h = e0 / 48, w = e0 % 48;
        float f[8];
        unpack8(*reinterpret_cast<const uint4*>(&ys[base0 + e0]), f);
        #pragma unroll
        for (int i = 0; i < 8; ++i) t0[h * 49 + w + i] = f[i];
        unpack8(*reinterpret_cast<const uint4*>(&ys[base2 + e0]), f);
        #pragma unroll
        for (int i = 0; i < 8; ++i) t2[h * 49 + w + i] = f[i];
    }
    __syncthreads();
    const size_t cbase = ((size_t)qb * CN + c) * LL;
    for (int idx = tid; idx < 288; idx += 256) {
        int m0 = idx * 8, ww = m0 / 48, hh = m0 % 48;
        float f1[8], f3[8];
        unpack8(*reinterpret_cast<const uint4*>(&ys[base1 + m0]), f1);
        unpack8(*reinterpret_cast<const uint4*>(&ys[base3 + (LL - 8 - m0)]), f3);
        float o[8];
        #pragma unroll
        for (int i = 0; i < 8; ++i) {
            float v0 = t0[(hh + i) * 49 + ww];
            float v2 = t2[(47 - hh - i) * 49 + (47 - ww)];
            o[i] = v0 + f1[i] + v2 + f3[7 - i];
        }
        uint4 w;
        w.x = packbf(o[0], o[1]); w.y = packbf(o[2], o[3]);
        w.z = packbf(o[4], o[5]); w.w = packbf(o[6], o[7]);
        *reinterpret_cast<uint4*>(&s_out[cbase + m0]) = w;
    }
}

// ============================================================================
// K5: combine: LN(ssln) + LN(p2n) + y=a*z + attention partial sums
// grid (48, 16, 4) = (ww, b, q), block 256
// ============================================================================
__global__ __launch_bounds__(256) void k_combine(
    const bf16* __restrict__ s_in, const bf16* __restrict__ a_in,
    const float* __restrict__ ssg, const float* __restrict__ ssb,
    const float* __restrict__ png, const float* __restrict__ pnb,
    const int* __restrict__ bidx,
    bf16* __restrict__ y_out, float* __restrict__ s_buf)
{
    const int ww = blockIdx.x, b = blockIdx.y, q = blockIdx.z;
    const int qb = q * BQ + b;
    const int tid = threadIdx.x;
    __shared__ float o[CN * 48];
    __shared__ float mu[48], rs[48];
    for (int v = tid; v < 576; v += 256) {
        int e0 = v * 8, cc = e0 / 48, hh = e0 % 48;
        float f[8];
        unpack8(*reinterpret_cast<const uint4*>(&s_in[((size_t)qb * CN + cc) * LL + ww * 48 + hh]), f);
        #pragma unroll
        for (int i = 0; i < 8; ++i) o[cc * 48 + hh + i] = f[i];
    }
    __syncthreads();
    if (tid < 48) {
        float s = 0.f, s2 = 0.f;
        for (int cc = 0; cc < CN; ++cc) { float v = o[cc * 48 + tid]; s += v; s2 += v * v; }
        float m = s * (1.f / 96.f), var = s2 * (1.f / 96.f) - m * m;
        mu[tid] = m; rs[tid] = rsqrtf(var + 1e-6f);
    }
    __syncthreads();
    for (int t = tid; t < CN * 48; t += 256) {
        int cc = t / 48, hh = t % 48;
        o[t] = (o[t] - mu[hh]) * rs[hh] * ssg[q * CN + cc] + ssb[q * CN + cc];
    }
    __syncthreads();
    if (tid < 48) {
        float s = 0.f, s2 = 0.f;
        for (int cc = 0; cc < CN; ++cc) { float v = o[cc * 48 + tid]; s += v; s2 += v * v; }
        float m = s * (1.f / 96.f), var = s2 * (1.f / 96.f) - m * m;
        mu[tid] = m; rs[tid] = rsqrtf(var + 1e-6f);
    }
    __syncthreads();
    const bool even = ((bidx[0] & 1) == 0);
    if (even) {
        for (int v = tid; v < 576; v += 256) {
            int e0 = v * 8, cc = e0 / 48, hh = e0 % 48;
            size_t oidx = ((size_t)qb * CN + cc) * LL + ww * 48 + hh;
            float af[8];
            unpack8(*reinterpret_cast<const uint4*>(&a_in[oidx]), af);
            float yv[8];
            #pragma unroll
            for (int i = 0; i < 8; ++i) {
                float z2 = (o[cc * 48 + hh + i] - mu[hh + i]) * rs[hh + i] * png[q * CN + cc] + pnb[q * CN + cc];
                yv[i] = af[i] * z2;
                o[cc * 48 + hh + i] = yv[i];
            }
            uint4 w;
            w.x = packbf(yv[0], yv[1]); w.y = packbf(yv[2], yv[3]);
            w.z = packbf(yv[4], yv[5]); w.w = packbf(yv[6], yv[7]);
            *reinterpret_cast<uint4*>(&y_out[oidx]) = w;
        }
    } else {
        for (int t = tid; t < CN * 48; t += 256) {
            int cc = t / 48, hh = t % 48;
            float z2 = (o[t] - mu[hh]) * rs[hh] * png[q * CN + cc] + pnb[q * CN + cc];
            size_t oidx = ((size_t)qb * CN + cc) * LL + (47 - hh) * 48 + (47 - ww);
            float yv = b2f(a_in[oidx]) * z2;
            y_out[oidx] = f2b(yv);
            o[t] = yv;
        }
    }
    __syncthreads();
    if (tid < CN) {
        float s = 0.f;
        for (int j = 0; j < 48; ++j) s += o[tid * 48 + j];
        atomicAdd(&s_buf[qb * CN + tid], s);
    }
}

// ============================================================================
// K7: out = x + y * att  with channel attention computed in-block
// grid (96, 16, 4) = (c, b, q), block 256
// ============================================================================
__global__ __launch_bounds__(256) void k_final(
    const float* __restrict__ x, const bf16* __restrict__ y_in,
    const float* __restrict__ s_buf,
    const float* __restrict__ w1, const float* __restrict__ b1,
    const float* __restrict__ w2, const float* __restrict__ b2,
    float* __restrict__ out)
{
    const int c = blockIdx.x, b = blockIdx.y, q = blockIdx.z;
    const int h0 = (q >> 1) * HQ, w0 = (q & 1) * HQ;
    const int qb = q * BQ + b;
    const int tid = threadIdx.x;
    __shared__ float tl[CRr];
    __shared__ float attv;
    if (tid < CRr) {
        float acc = b1[q * CRr + tid];
        const float* wr = w1 + (q * CRr + tid) * CN;
        const float* sb = s_buf + qb * CN;
        for (int cc = 0; cc < CN; ++cc)
            acc = fmaf(wr[cc], sb[cc] * (1.f / (float)LL), acc);
        tl[tid] = siluf(acc);
    }
    __syncthreads();
    if (tid == 0) {
        float acc = b2[q * CN + c];
        #pragma unroll
        for (int r = 0; r < CRr; ++r) acc = fmaf(w2[(q * CN + c) * CRr + r], tl[r], acc);
        attv = sigf(acc);
    }
    __syncthreads();
    const float av = attv;
    const size_t ybase = (size_t)(qb * CN + c) * LL;
    const int xb = (b * CN + c) * 9216 + h0 * 96 + w0;
    for (int t = tid; t < LL / 8; t += 256) {
        int e0 = t * 8;
        int gi = xb + (e0 / 48) * 96 + (e0 % 48);
        uint4 yv = *reinterpret_cast<const uint4*>(&y_in[ybase + e0]);
        float yf[8]; unpack8(yv, yf);
        float4 xa = *reinterpret_cast<const float4*>(&x[gi]);
        float4 xc = *reinterpret_cast<const float4*>(&x[gi + 4]);
        float4 o0 = {xa.x + yf[0]*av, xa.y + yf[1]*av, xa.z + yf[2]*av, xa.w + yf[3]*av};
        float4 o1 = {xc.x + yf[4]*av, xc.y + yf[5]*av, xc.z + yf[6]*av, xc.w + yf[7]*av};
        *reinterpret_cast<float4*>(&out[gi])     = o0;
        *reinterpret_cast<float4*>(&out[gi + 4]) = o1;
    }
}

// ============================================================================
extern "C" void kernel_launch(void* const* d_in, const int* in_sizes, int n_in,
                              void* d_out, int out_size, void* d_ws, size_t ws_size,
                              hipStream_t stream)
{
    (void)in_sizes; (void)n_in; (void)out_size; (void)ws_size;
    const float* x       = (const float*)d_in[0];
    const float* ln_g    = (const float*)d_in[1];
    const float* ln_b    = (const float*)d_in[2];
    const float* p1_w    = (const float*)d_in[3];
    const float* p1_b    = (const float*)d_in[4];
    const float* p2in_w  = (const float*)d_in[5];
    const float* p2in_b  = (const float*)d_in[6];
    const float* dw_w    = (const float*)d_in[7];
    const float* dw_b    = (const float*)d_in[8];
    const float* xproj_w = (const float*)d_in[9];
    const float* dtproj_w= (const float*)d_in[10];
    const float* dtproj_b= (const float*)d_in[11];
    const float* A_logs  = (const float*)d_in[12];
    const float* Ds      = (const float*)d_in[13];
    const float* ssln_g  = (const float*)d_in[14];
    const float* ssln_b  = (const float*)d_in[15];
    const float* p2n_g   = (const float*)d_in[16];
    const float* p2n_b   = (const float*)d_in[17];
    const float* ca_w1   = (const float*)d_in[18];
    const float* ca_b1   = (const float*)d_in[19];
    const float* ca_w2   = (const float*)d_in[20];
    const float* ca_b2   = (const float*)d_in[21];
    const int*  bidx     = (const int*)d_in[22];
    float* out = (float*)d_out;

    char* ws = (char*)d_ws;
    const size_t off_a    = 0;                                  // bf16, live K1->K5
    const size_t off_zt   = 28311552;                           // bf16, live K2->K4
    const size_t off_ztT  = 56623104;                           // bf16, live K2->K4
    const size_t off_xdbl = 84934656;                           // bf16, live K3->K4
    const size_t off_ys   = 110886912;                          // bf16, live K4->K4b
    const size_t off_z0   = off_ys;                             // bf16 alias (dead before ys)
    const size_t off_s    = off_zt;                             // bf16 alias: sum tensor (K4b->K5)
    const size_t off_y    = off_ztT;                            // bf16 alias: gated y (K5->K7)
    const size_t off_sb   = 224133120;                          // fp32 attention sums

    bf16*  a_buf   = (bf16*)(ws + off_a);
    bf16*  zt_buf  = (bf16*)(ws + off_zt);
    bf16*  ztT_buf = (bf16*)(ws + off_ztT);
    bf16*  xdbl_buf= (bf16*)(ws + off_xdbl);
    bf16*  ys_buf  = (bf16*)(ws + off_ys);
    bf16*  z0_buf  = (bf16*)(ws + off_z0);
    bf16*  s_sum   = (bf16*)(ws + off_s);
    bf16*  y_buf   = (bf16*)(ws + off_y);
    float* s_buf   = (float*)(ws + off_sb);

    (void)hipMemsetAsync(ws + off_sb, 0, 24576, stream);

    k_lnconv<<<dim3(24, 16, 4), 192, 0, stream>>>(
        x, ln_g, ln_b, p1_w, p1_b, p2in_w, p2in_b, a_buf, z0_buf);
    k_dwconv<<<dim3(96, 16, 4), 256, 0, stream>>>(
        z0_buf, dw_w, dw_b, bidx, zt_buf, ztT_buf);
    k_xdbl<<<dim3(12, 4, 64), 256, 0, stream>>>(
        zt_buf, ztT_buf, xproj_w, xdbl_buf);
    k_scan<<<dim3(512), 192, 0, stream>>>(
        zt_buf, ztT_buf, xdbl_buf, dtproj_w, dtproj_b, A_logs, Ds, ys_buf);
    k_sum<<<dim3(96, 16, 4), 256, 0, stream>>>(
        ys_buf, s_sum);
    k_combine<<<dim3(48, 16, 4), 256, 0, stream>>>(
        s_sum, a_buf, ssln_g, ssln_b, p2n_g, p2n_b, bidx, y_buf, s_buf);
    k_final<<<dim3(96, 16, 4), 256, 0, stream>>>(
        x, y_buf, s_buf, ca_w1, ca_b1, ca_w2, ca_b2, out);
}